// Round 9
// baseline (1625.983 us; speedup 1.0000x reference)
//
#include <hip/hip_runtime.h>
#include <hip/hip_bf16.h>
#include <math.h>
#include <type_traits>
#include <utility>

// ---------------- problem constants ----------------
#define DMODEL 768
#define NTOK 197
#define NIMG 8            // B*NV
#define NHEADS 12
#define MLPD 3072
#define NROWS (NIMG*NTOK)     // 1576
#define NPATCH (NIMG*196)     // 1568
#define HF 14
#define BATCH 2
#define NCELL (BATCH*HF*HF)   // 392
#define FD 256

typedef __attribute__((ext_vector_type(8))) short s8v;
typedef __attribute__((ext_vector_type(8))) __bf16 b8v;
typedef __attribute__((ext_vector_type(8))) _Float16 h8v;
typedef __attribute__((ext_vector_type(4))) float f32x4;

// ---- MFMA builtin operand-type pickers (vector elt type varies across ROCm) ----
template <typename V, typename = void>
struct mfma_takes : std::false_type {};
template <typename V>
struct mfma_takes<V, std::void_t<decltype(
    __builtin_amdgcn_mfma_f32_16x16x32_bf16(std::declval<V>(), std::declval<V>(),
                                            std::declval<f32x4>(), 0, 0, 0))>>
    : std::true_type {};

template <typename V>
struct MfmaCall {
    static __device__ inline f32x4 run(s8v a, s8v b, f32x4 c) {
        return __builtin_amdgcn_mfma_f32_16x16x32_bf16(
            __builtin_bit_cast(V, a), __builtin_bit_cast(V, b), c, 0, 0, 0);
    }
};
using mfma_v = std::conditional_t<mfma_takes<b8v>::value, b8v, s8v>;

template <typename V, typename = void>
struct mfma16_takes : std::false_type {};
template <typename V>
struct mfma16_takes<V, std::void_t<decltype(
    __builtin_amdgcn_mfma_f32_16x16x32_f16(std::declval<V>(), std::declval<V>(),
                                           std::declval<f32x4>(), 0, 0, 0))>>
    : std::true_type {};

template <typename V>
struct MfmaF16Call {
    static __device__ inline f32x4 run(s8v a, s8v b, f32x4 c) {
        return __builtin_amdgcn_mfma_f32_16x16x32_f16(
            __builtin_bit_cast(V, a), __builtin_bit_cast(V, b), c, 0, 0, 0);
    }
};
using mfma16_v = std::conditional_t<mfma16_takes<h8v>::value, h8v, s8v>;

typedef __attribute__((address_space(1))) const unsigned int guint_t;
typedef __attribute__((address_space(3))) unsigned int luint_t;

// ---------------- bf16 MFMA GEMM: 3-slot ring buffer + counted vmcnt ----------------
// C[M,N] = epilogue(A[M,K] @ B[K,N]), B supplied TRANSPOSED: BT[N][K].
// BK=32, 4 waves 2x2, wave tile (BM/2)x(BN/2), global_load_lds staging.
// Pipeline: 2 tiles in flight, raw s_barrier (no vmcnt drain), counted
// s_waitcnt vmcnt(LPS) so the newest prefetch stays in flight (T3/T4).
// flags: bit0=GELU, bit1=bf16 out, bit2=f16 out, bit3=raw fp32 partial
// grid: x = nx*ny flattened (XCD-swizzled), z = split-K index
template <int BM, int BN>
__global__ __launch_bounds__(256) void gemm_t(
    const __hip_bfloat16* __restrict__ A, const __hip_bfloat16* __restrict__ BT,
    const float* __restrict__ bias, const float* __restrict__ res,
    void* __restrict__ Cout, int M, int N, int K, int flags, int nx,
    float* __restrict__ part)
{
    constexpr int FM = BM / 32;
    constexpr int FN = BN / 32;
    constexpr int LPS = (BM * 4 + BN * 4) / 256;   // loads per thread per stage
    __shared__ short Asl[3][BM * 32];
    __shared__ short Bsl[3][BN * 32];
    int t = threadIdx.x;
    int w = t >> 6, lane = t & 63;

    // bijective XCD swizzle (m204)
    int nwg = gridDim.x;
    int id = blockIdx.x;
    int q = nwg >> 3, r = nwg & 7;
    int xcd = id & 7;
    int wgid = (xcd < r ? xcd * (q + 1) : r * (q + 1) + (xcd - r) * q) + (id >> 3);
    int bx = wgid % nx, by = wgid / nx;
    int bm = by * BM, bn = bx * BN;

    int S = gridDim.z, z = blockIdx.z;
    int kchunk = K / S;
    int kbeg = z * kchunk;
    int nk = kchunk >> 5;

    int rbase = (w >> 1) * (BM / 2), cbase = (w & 1) * (BN / 2);

    f32x4 acc[FM][FN];
    #pragma unroll
    for (int i = 0; i < FM; i++)
        #pragma unroll
        for (int j = 0; j < FN; j++)
            acc[i][j] = (f32x4){0.f, 0.f, 0.f, 0.f};

    const short* Ag = (const short*)A;
    const short* Bg = (const short*)BT;

    auto STAGE = [&](int buf, int k0) {
        #pragma unroll
        for (int i = 0; i < BM * 4 / 256; i++) {
            int c = i * 256 + t;
            int row = c >> 2, koff = (c & 3) * 8;
            int ga = bm + row; if (ga >= M) ga = M - 1;
            __builtin_amdgcn_global_load_lds(
                (guint_t*)(Ag + (size_t)ga * K + k0 + koff),
                (luint_t*)(&Asl[buf][0] + c * 8), 16, 0, 0);
        }
        #pragma unroll
        for (int i = 0; i < BN * 4 / 256; i++) {
            int c = i * 256 + t;
            int row = c >> 2, koff = (c & 3) * 8;
            __builtin_amdgcn_global_load_lds(
                (guint_t*)(Bg + (size_t)(bn + row) * K + k0 + koff),
                (luint_t*)(&Bsl[buf][0] + c * 8), 16, 0, 0);
        }
    };

    STAGE(0, kbeg);
    if (nk > 1) STAGE(1, kbeg + 32);
    int kk = (lane >> 4) * 8;
    int rl = lane & 15;

    for (int kt = 0; kt < nk; kt++) {
        int cur = kt % 3;
        // wait for tile kt (older than the <=LPS newest outstanding loads)
        if (kt + 1 < nk) {
            if constexpr (LPS == 2)      asm volatile("s_waitcnt vmcnt(2)" ::: "memory");
            else if constexpr (LPS == 3) asm volatile("s_waitcnt vmcnt(3)" ::: "memory");
            else                         asm volatile("s_waitcnt vmcnt(4)" ::: "memory");
        } else {
            asm volatile("s_waitcnt vmcnt(0)" ::: "memory");
        }
        __builtin_amdgcn_sched_barrier(0);
        __builtin_amdgcn_s_barrier();      // all waves: tile kt landed, tile kt-1 consumed
        __builtin_amdgcn_sched_barrier(0);
        if (kt + 2 < nk) STAGE((kt + 2) % 3, kbeg + (kt + 2) * 32);

        s8v af[FM], bfr[FN];
        #pragma unroll
        for (int i = 0; i < FM; i++)
            af[i] = *(const s8v*)(&Asl[cur][0] + (rbase + i * 16 + rl) * 32 + kk);
        #pragma unroll
        for (int j = 0; j < FN; j++)
            bfr[j] = *(const s8v*)(&Bsl[cur][0] + (cbase + j * 16 + rl) * 32 + kk);
        #pragma unroll
        for (int i = 0; i < FM; i++)
            #pragma unroll
            for (int j = 0; j < FN; j++)
                acc[i][j] = MfmaCall<mfma_v>::run(af[i], bfr[j], acc[i][j]);
    }

    int colg = lane & 15;
    int rowg = (lane >> 4) * 4;
    #pragma unroll
    for (int i = 0; i < FM; i++) {
        #pragma unroll
        for (int j = 0; j < FN; j++) {
            #pragma unroll
            for (int qq = 0; qq < 4; qq++) {
                int rr = bm + rbase + i * 16 + rowg + qq;
                int cc = bn + cbase + j * 16 + colg;
                if (rr < M) {
                    float v = acc[i][j][qq];
                    if (flags & 8) {
                        part[((size_t)z * M + rr) * N + cc] = v;
                    } else {
                        if (bias) v += bias[cc];
                        if (flags & 1) v = 0.5f * v * (1.0f + erff(v * 0.7071067811865476f));
                        if (res)  v += res[(size_t)rr * N + cc];
                        if (flags & 2)
                            ((__hip_bfloat16*)Cout)[(size_t)rr * N + cc] = __float2bfloat16(v);
                        else if (flags & 4)
                            ((_Float16*)Cout)[(size_t)rr * N + cc] = (_Float16)v;
                        else
                            ((float*)Cout)[(size_t)rr * N + cc] = v;
                    }
                }
            }
        }
    }
}

// ---------------- fused reduce + LayerNorm ----------------
// tok' = tok + sum(part[0..NPART)) + bias ; h = LN(tok') -> bf16 (or fp32 final)
template <int NPART, int FINAL>
__global__ __launch_bounds__(256) void redln_kernel(
    const float* __restrict__ part, const float* __restrict__ bias,
    float* __restrict__ tok, const float* __restrict__ g,
    const float* __restrict__ b, __hip_bfloat16* __restrict__ hout,
    float* __restrict__ fout)
{
    int r = blockIdx.x, t = threadIdx.x;
    __shared__ float red[8];
    float v[3];
    #pragma unroll
    for (int i = 0; i < 3; i++) {
        int idx = t + i * 256;
        float x = tok[(size_t)r * DMODEL + idx] + bias[idx];
        #pragma unroll
        for (int p = 0; p < NPART; p++)
            x += part[((size_t)p * NROWS + r) * DMODEL + idx];
        v[i] = x;
        if (!FINAL) tok[(size_t)r * DMODEL + idx] = x;
    }
    float s = v[0] + v[1] + v[2];
    #pragma unroll
    for (int m = 32; m >= 1; m >>= 1) s += __shfl_xor(s, m);
    int wid = t >> 6, lane = t & 63;
    if (lane == 0) red[wid] = s;
    __syncthreads();
    float mean = (red[0] + red[1] + red[2] + red[3]) * (1.0f / DMODEL);
    float d0 = v[0] - mean, d1 = v[1] - mean, d2 = v[2] - mean;
    float qv = d0 * d0 + d1 * d1 + d2 * d2;
    #pragma unroll
    for (int m = 32; m >= 1; m >>= 1) qv += __shfl_xor(qv, m);
    __syncthreads();
    if (lane == 0) red[4 + wid] = qv;
    __syncthreads();
    float var = (red[4] + red[5] + red[6] + red[7]) * (1.0f / DMODEL);
    float rs = 1.0f / sqrtf(var + 1e-6f);
    float dd[3] = {d0, d1, d2};
    #pragma unroll
    for (int i = 0; i < 3; i++) {
        int idx = t + i * 256;
        float y = dd[i] * rs * g[idx] + b[idx];
        if (FINAL) fout[(size_t)r * DMODEL + idx] = y;
        else       hout[(size_t)r * DMODEL + idx] = __float2bfloat16(y);
    }
}

// layer-0 entry: tok = assemble(cls/patch + pos); h = LN(tok)
__global__ __launch_bounds__(256) void assemble_ln_kernel(
    const float* __restrict__ tmp, const float* __restrict__ cls,
    const float* __restrict__ pos, const float* __restrict__ g,
    const float* __restrict__ b, float* __restrict__ tok,
    __hip_bfloat16* __restrict__ hout)
{
    int rr = blockIdx.x;
    int n = rr / NTOK, r = rr % NTOK;
    int t = threadIdx.x;
    __shared__ float red[8];
    float v[3];
    #pragma unroll
    for (int i = 0; i < 3; i++) {
        int idx = t + i * 256;
        float x = (r == 0) ? cls[idx]
                           : tmp[((size_t)n * 196 + r - 1) * DMODEL + idx];
        x += pos[(size_t)r * DMODEL + idx];
        v[i] = x;
        tok[(size_t)rr * DMODEL + idx] = x;
    }
    float s = v[0] + v[1] + v[2];
    #pragma unroll
    for (int m = 32; m >= 1; m >>= 1) s += __shfl_xor(s, m);
    int wid = t >> 6, lane = t & 63;
    if (lane == 0) red[wid] = s;
    __syncthreads();
    float mean = (red[0] + red[1] + red[2] + red[3]) * (1.0f / DMODEL);
    float d0 = v[0] - mean, d1 = v[1] - mean, d2 = v[2] - mean;
    float qv = d0 * d0 + d1 * d1 + d2 * d2;
    #pragma unroll
    for (int m = 32; m >= 1; m >>= 1) qv += __shfl_xor(qv, m);
    __syncthreads();
    if (lane == 0) red[4 + wid] = qv;
    __syncthreads();
    float var = (red[4] + red[5] + red[6] + red[7]) * (1.0f / DMODEL);
    float rs = 1.0f / sqrtf(var + 1e-6f);
    float dd[3] = {d0, d1, d2};
    #pragma unroll
    for (int i = 0; i < 3; i++) {
        int idx = t + i * 256;
        hout[(size_t)rr * DMODEL + idx] = __float2bfloat16(dd[i] * rs * g[idx] + b[idx]);
    }
}

// ---------------- fused attention (f16 MFMA, 64-row q blocks, 2 blocks/CU) ----
#define AT_STR 232     // P / Vt row stride in f16
#define KS_STR 72      // Q / K row stride in f16

__global__ __launch_bounds__(256) void fused_attn_kernel(
    const _Float16* __restrict__ qkv, __hip_bfloat16* __restrict__ O)
{
    __shared__ char smem[29696 + 39168];              // 67.25 KB -> 2 blocks/CU
    _Float16* Vt = (_Float16*)smem;                   // [64][232]
    _Float16* Qs = (_Float16*)(smem + 29696);         // [64][72]
    _Float16* Ks = Qs + 64 * KS_STR;                  // [208][72]
    _Float16* Pl = (_Float16*)(smem + 29696);         // alias: [64][232]

    int nh = blockIdx.x;            // 0..95
    int n = nh / NHEADS, hh = nh % NHEADS;
    int qoff = blockIdx.y * 64;
    int t = threadIdx.x;
    int w = t >> 6, lane = t & 63;
    int g = lane >> 4, rl = lane & 15;
    const _Float16* base = qkv + (size_t)n * NTOK * 2304;

    // ---- stage K (rows >=197 zeroed), Q (clamped), V^T ----
    for (int idx = t; idx < 208 * 8; idx += 256) {
        int row = idx >> 3, c8 = (idx & 7) * 8;
        if (row < NTOK)
            *(uint4*)(Ks + row * KS_STR + c8) =
                *(const uint4*)(base + (size_t)row * 2304 + 768 + hh * 64 + c8);
        else
            *(uint4*)(Ks + row * KS_STR + c8) = make_uint4(0, 0, 0, 0);
    }
    for (int idx = t; idx < 64 * 8; idx += 256) {
        int row = idx >> 3, c8 = (idx & 7) * 8;
        int gq = qoff + row; if (gq > NTOK - 1) gq = NTOK - 1;
        *(uint4*)(Qs + row * KS_STR + c8) =
            *(const uint4*)(base + (size_t)gq * 2304 + hh * 64 + c8);
    }
    for (int idx = t; idx < NTOK * 8; idx += 256) {
        int k = idx >> 3, dg = (idx & 7) * 8;
        _Float16 tmp[8];
        *(uint4*)tmp = *(const uint4*)(base + (size_t)k * 2304 + 1536 + hh * 64 + dg);
        #pragma unroll
        for (int j = 0; j < 8; j++) Vt[(dg + j) * AT_STR + k] = tmp[j];
    }
    for (int idx = t; idx < 64 * 27; idx += 256) {     // zero Vt cols 197..223
        int d = idx / 27, k = NTOK + idx % 27;
        Vt[d * AT_STR + k] = (_Float16)0.f;
    }
    __syncthreads();

    // ---- S = Q K^T : wave handles 16 q rows x 13 k-tiles ----
    int wq0 = w * 16;
    f32x4 sacc[13];
    #pragma unroll
    for (int tt = 0; tt < 13; tt++) sacc[tt] = (f32x4){0.f, 0.f, 0.f, 0.f};

    #pragma unroll
    for (int s = 0; s < 2; s++) {
        s8v af = *(const s8v*)(Qs + (wq0 + rl) * KS_STR + s * 32 + 8 * g);
        #pragma unroll
        for (int tt = 0; tt < 13; tt++) {
            s8v bf = *(const s8v*)(Ks + (tt * 16 + rl) * KS_STR + s * 32 + 8 * g);
            sacc[tt] = MfmaF16Call<mfma16_v>::run(af, bf, sacc[tt]);
        }
    }
    __syncthreads();   // all waves done reading Qs/Ks before P overwrites

    // ---- softmax (lane holds col=rl+16*tt for row g*4+r) ----
    _Float16* Pw = Pl + wq0 * AT_STR;
    #pragma unroll
    for (int r = 0; r < 4; r++) {
        float vv[13];
        float mx = -3.0e38f;
        #pragma unroll
        for (int tt = 0; tt < 13; tt++) {
            float v = sacc[tt][r] * 0.125f;
            vv[tt] = v;
            if (rl + 16 * tt < NTOK) mx = fmaxf(mx, v);
        }
        mx = fmaxf(mx, __shfl_xor(mx, 1));
        mx = fmaxf(mx, __shfl_xor(mx, 2));
        mx = fmaxf(mx, __shfl_xor(mx, 4));
        mx = fmaxf(mx, __shfl_xor(mx, 8));
        float pv[13];
        float sum = 0.f;
        #pragma unroll
        for (int tt = 0; tt < 13; tt++) {
            float p = (rl + 16 * tt < NTOK) ? __expf(vv[tt] - mx) : 0.f;
            pv[tt] = p; sum += p;
        }
        sum += __shfl_xor(sum, 1);
        sum += __shfl_xor(sum, 2);
        sum += __shfl_xor(sum, 4);
        sum += __shfl_xor(sum, 8);
        float rinv = 1.0f / sum;
        int prow = g * 4 + r;
        #pragma unroll
        for (int tt = 0; tt < 13; tt++)
            Pw[prow * AT_STR + rl + 16 * tt] = (_Float16)(pv[tt] * rinv);
    }
    for (int idx = lane; idx < 16 * 16; idx += 64) {   // zero P cols 208..223
        int rr = idx >> 4, cc = 208 + (idx & 15);
        Pw[rr * AT_STR + cc] = (_Float16)0.f;
    }
    // no barrier: each wave reads only its own Pw region + stable Vt

    // ---- O = P V : 4 n-tiles, 7 k-steps ----
    f32x4 oacc[4];
    #pragma unroll
    for (int j = 0; j < 4; j++) oacc[j] = (f32x4){0.f, 0.f, 0.f, 0.f};

    for (int s = 0; s < 7; s++) {
        s8v pf = *(const s8v*)(Pw + rl * AT_STR + s * 32 + 8 * g);
        s8v vf[4];
        #pragma unroll
        for (int j = 0; j < 4; j++)
            vf[j] = *(const s8v*)(Vt + (j * 16 + rl) * AT_STR + s * 32 + 8 * g);
        #pragma unroll
        for (int j = 0; j < 4; j++)
            oacc[j] = MfmaF16Call<mfma16_v>::run(pf, vf[j], oacc[j]);
    }

    #pragma unroll
    for (int j = 0; j < 4; j++) {
        #pragma unroll
        for (int r = 0; r < 4; r++) {
            int qidx = qoff + wq0 + g * 4 + r;
            if (qidx < NTOK) {
                int d = j * 16 + rl;
                O[((size_t)n * NTOK + qidx) * DMODEL + hh * 64 + d] =
                    __float2bfloat16(oacc[j][r]);
            }
        }
    }
}

// ---------------- weight convert + transpose (fp32 [K][N] -> bf16 [N][K]) ----
// 32K x 128N tile: 512B coalesced fp32 reads/row, conflict-free LDS, 32B writes.
__device__ inline void transpose_tile_wide(const float* __restrict__ src,
                                           __hip_bfloat16* __restrict__ dst,
                                           int K, int N, int b)
{
    __shared__ float tl[32][129];
    int ntn = N >> 7;
    int n0 = (b % ntn) * 128, k0 = (b / ntn) * 32;
    int t = threadIdx.x;
    #pragma unroll
    for (int i = 0; i < 16; i++) {
        int idx = i * 256 + t;
        int kk = idx >> 7, nn = idx & 127;
        tl[kk][nn] = src[(size_t)(k0 + kk) * N + n0 + nn];
    }
    __syncthreads();
    int n = t >> 1, kc = (t & 1) * 16;
    __hip_bfloat16 v[16];
    #pragma unroll
    for (int j = 0; j < 16; j++) v[j] = __float2bfloat16(tl[kc + j][n]);
    *(uint4*)(dst + (size_t)(n0 + n) * K + k0 + kc)     = *(uint4*)&v[0];
    *(uint4*)(dst + (size_t)(n0 + n) * K + k0 + kc + 8) = *(uint4*)&v[8];
}

// one dispatch: all 12 layers (qkv|proj|fc1|fc2) + patch_w
// per-layer tiles: qkv 432, proj 144, fc1 576, fc2 576 = 1728; patch 144
__global__ __launch_bounds__(256) void convT_all(
    const float* __restrict__ qkv_w, const float* __restrict__ proj_w,
    const float* __restrict__ fc1_w, const float* __restrict__ fc2_w,
    const float* __restrict__ patch_w,
    __hip_bfloat16* __restrict__ wbuf, __hip_bfloat16* __restrict__ patchT)
{
    int b = blockIdx.x;
    if (b < 20736) {
        int layer = b / 1728, rem = b % 1728;
        __hip_bfloat16* wl = wbuf + (size_t)layer * 7077888;
        const float* src; __hip_bfloat16* dst; int K, N, tb;
        if (rem < 432)       { tb = rem;        src = qkv_w  + (size_t)layer * 768 * 2304; dst = wl;           K = 768;  N = 2304; }
        else if (rem < 576)  { tb = rem - 432;  src = proj_w + (size_t)layer * 768 * 768;  dst = wl + 1769472; K = 768;  N = 768;  }
        else if (rem < 1152) { tb = rem - 576;  src = fc1_w  + (size_t)layer * 768 * 3072; dst = wl + 2359296; K = 768;  N = 3072; }
        else                 { tb = rem - 1152; src = fc2_w  + (size_t)layer * 3072 * 768; dst = wl + 4718592; K = 3072; N = 768;  }
        transpose_tile_wide(src, dst, K, N, tb);
    } else {
        transpose_tile_wide(patch_w, patchT, 768, 768, b - 20736);
    }
}

// ---------------- patch extraction (fp32 img -> bf16 patch matrix) ----------------
__global__ __launch_bounds__(256) void patch_extract_kernel(
    const float* __restrict__ img, __hip_bfloat16* __restrict__ Pm)
{
    size_t e = (size_t)blockIdx.x * 256 + threadIdx.x;
    if (e >= (size_t)NPATCH * DMODEL) return;
    int cidx = (int)(e % DMODEL);
    int r    = (int)(e / DMODEL);
    int n  = r / 196, s = r % 196;
    int hi = s / HF, wi = s % HF;
    int c  = cidx >> 8, py = (cidx >> 4) & 15, px = cidx & 15;
    Pm[e] = __float2bfloat16(
        img[(((size_t)n * 3 + c) * 224 + hi * 16 + py) * 224 + wi * 16 + px]);
}

// ---------------- 4x4 inverse (adjugate) ----------------
__device__ void invert4(const float m[16], float out[16]) {
    float inv[16];
    inv[0] = m[5]*m[10]*m[15] - m[5]*m[11]*m[14] - m[9]*m[6]*m[15] + m[9]*m[7]*m[14] + m[13]*m[6]*m[11] - m[13]*m[7]*m[10];
    inv[4] = -m[4]*m[10]*m[15] + m[4]*m[11]*m[14] + m[8]*m[6]*m[15] - m[8]*m[7]*m[14] - m[12]*m[6]*m[11] + m[12]*m[7]*m[10];
    inv[8] = m[4]*m[9]*m[15] - m[4]*m[11]*m[13] - m[8]*m[5]*m[15] + m[8]*m[7]*m[13] + m[12]*m[5]*m[11] - m[12]*m[7]*m[9];
    inv[12] = -m[4]*m[9]*m[14] + m[4]*m[10]*m[13] + m[8]*m[5]*m[14] - m[8]*m[6]*m[13] - m[12]*m[5]*m[10] + m[12]*m[6]*m[9];
    inv[1] = -m[1]*m[10]*m[15] + m[1]*m[11]*m[14] + m[9]*m[2]*m[15] - m[9]*m[3]*m[14] - m[13]*m[2]*m[11] + m[13]*m[3]*m[10];
    inv[5] = m[0]*m[10]*m[15] - m[0]*m[11]*m[14] - m[8]*m[2]*m[15] + m[8]*m[3]*m[14] + m[12]*m[2]*m[11] - m[12]*m[3]*m[10];
    inv[9] = -m[0]*m[9]*m[15] + m[0]*m[11]*m[13] + m[8]*m[1]*m[15] - m[8]*m[3]*m[13] - m[12]*m[1]*m[11] + m[12]*m[3]*m[9];
    inv[13] = m[0]*m[9]*m[14] - m[0]*m[10]*m[13] - m[8]*m[1]*m[14] + m[8]*m[2]*m[13] + m[12]*m[1]*m[10] - m[12]*m[2]*m[9];
    inv[2] = m[1]*m[6]*m[15] - m[1]*m[7]*m[14] - m[5]*m[2]*m[15] + m[5]*m[3]*m[14] + m[13]*m[2]*m[7] - m[13]*m[3]*m[6];
    inv[6] = -m[0]*m[6]*m[15] + m[0]*m[7]*m[14] + m[4]*m[2]*m[15] - m[4]*m[3]*m[14] - m[12]*m[2]*m[7] + m[12]*m[3]*m[6];
    inv[10] = m[0]*m[5]*m[15] - m[0]*m[7]*m[13] - m[4]*m[1]*m[15] + m[4]*m[3]*m[13] + m[12]*m[1]*m[7] - m[12]*m[3]*m[5];
    inv[14] = -m[0]*m[5]*m[14] + m[0]*m[6]*m[13] + m[4]*m[1]*m[14] - m[4]*m[2]*m[13] - m[12]*m[1]*m[6] + m[12]*m[2]*m[5];
    inv[3] = -m[1]*m[6]*m[11] + m[1]*m[7]*m[10] + m[5]*m[2]*m[11] - m[5]*m[3]*m[10] - m[9]*m[2]*m[7] + m[9]*m[3]*m[6];
    inv[7] = m[0]*m[6]*m[11] - m[0]*m[7]*m[10] - m[4]*m[2]*m[11] + m[4]*m[3]*m[10] + m[8]*m[2]*m[7] - m[8]*m[3]*m[6];
    inv[11] = -m[0]*m[5]*m[11] + m[0]*m[7]*m[9] + m[4]*m[1]*m[11] - m[4]*m[3]*m[9] - m[8]*m[1]*m[7] + m[8]*m[3]*m[5];
    inv[15] = m[0]*m[5]*m[10] - m[0]*m[6]*m[9] - m[4]*m[1]*m[10] + m[4]*m[2]*m[9] + m[8]*m[1]*m[6] - m[8]*m[2]*m[5];
    float det = m[0]*inv[0] + m[1]*inv[4] + m[2]*inv[8] + m[3]*inv[12];
    det = 1.0f / det;
    for (int i = 0; i < 16; i++) out[i] = inv[i] * det;
}

// ---------------- BEV index / validity ----------------
__global__ __launch_bounds__(256) void bev_index_kernel(
    const float* __restrict__ depths, const float* __restrict__ poses,
    const float* __restrict__ intr, int* __restrict__ idxbuf)
{
    int bv = blockIdx.x;          // 0..7
    int b  = bv / 4;
    __shared__ float c2w[16];
    if (threadIdx.x == 0) {
        float w2c[16];
        const float* Pm = poses + bv * 16;
        const int perm[4] = {1, 0, 2, 3};
        for (int i = 0; i < 4; i++)
            for (int j = 0; j < 4; j++)
                w2c[i * 4 + j] = Pm[perm[i] * 4 + j];
        invert4(w2c, c2w);
    }
    __syncthreads();
    int t = threadIdx.x;
    if (t >= 196) return;
    int hh = t / HF, ww = t % HF;
    const float* dp = depths + (size_t)bv * 224 * 224;
    int r0 = hh * 16 + 7, c0 = ww * 16 + 7;
    float d = 0.25f * (dp[r0 * 224 + c0] + dp[r0 * 224 + c0 + 1] +
                       dp[(r0 + 1) * 224 + c0] + dp[(r0 + 1) * 224 + c0 + 1]);
    d *= 65.535f;
    bool mask = (d > 0.0f) && (d < 5.0f);
    float fx = intr[bv * 9 + 0], fy = intr[bv * 9 + 4];
    float cx = intr[bv * 9 + 2], cy = intr[bv * 9 + 5];
    float u = (float)ww, v = (float)hh;
    float Xc = -((u - cx) * d / (fx + 1e-8f));
    float Yc = (v - cy) * d / (fy + 1e-8f);
    float Xw = c2w[0] * Xc + c2w[1] * Yc + c2w[2] * d + c2w[3];
    float Yw = c2w[4] * Xc + c2w[5] * Yc + c2w[6] * d + c2w[7];
    float px = Xw * 1.4f + 7.0f;
    float py = -(Yw * 1.4f) + 7.0f;
    int pxi = (int)rintf(px);
    int pyi = (int)rintf(py);
    bool inb = (pxi >= 0) && (pxi < HF) && (pyi >= 0) && (pyi < HF);
    idxbuf[bv * 196 + t] = (mask && inb) ? (b * 196 + pyi * HF + pxi) : -1;
}

// ---------------- scatter (segment sum / count / max) ----------------
__global__ __launch_bounds__(256) void splat_kernel(
    const float* __restrict__ src, const int* __restrict__ idxbuf,
    float* __restrict__ ssum, float* __restrict__ smax, float* __restrict__ cnt)
{
    int r = blockIdx.x;              // 0..1567
    int idx = idxbuf[r];
    if (idx < 0) return;
    int bv = r / 196, s = r % 196;
    const float* row = src + ((size_t)bv * NTOK + 1 + s) * DMODEL;
    int t = threadIdx.x;
    for (int d = t; d < DMODEL; d += 256) {
        float v = row[d];
        atomicAdd(&ssum[(size_t)idx * DMODEL + d], v);
        atomicMax((int*)(smax + (size_t)idx * DMODEL + d), __float_as_int(v));
    }
    if (t == 0) atomicAdd(&cnt[idx], 1.0f);
}

// ---------------- bev combine + 1x1 conv ----------------
__global__ __launch_bounds__(256) void bev_conv_kernel(
    const float* __restrict__ ssum, const float* __restrict__ smax,
    const float* __restrict__ cnt, const float* __restrict__ convw,
    const float* __restrict__ convb, float* __restrict__ out)
{
    int cell = blockIdx.x;           // 0..391
    __shared__ float bev[DMODEL];
    int t = threadIdx.x;
    float c = cnt[cell];
    for (int d = t; d < DMODEL; d += 256)
        bev[d] = 0.5f * (ssum[(size_t)cell * DMODEL + d] / (c + 1e-8f) +
                         smax[(size_t)cell * DMODEL + d]);
    __syncthreads();
    float acc = convb[t];
    const float4* wr = (const float4*)(convw + (size_t)t * DMODEL);
    #pragma unroll 4
    for (int dc = 0; dc < DMODEL / 4; dc++) {
        float4 w4 = wr[dc];
        acc += bev[dc * 4 + 0] * w4.x + bev[dc * 4 + 1] * w4.y +
               bev[dc * 4 + 2] * w4.z + bev[dc * 4 + 3] * w4.w;
    }
    int b = cell / 196, s = cell % 196;
    out[((size_t)b * FD + t) * 196 + s] = acc;
}

// ---------------- host launcher ----------------
extern "C" void kernel_launch(void* const* d_in, const int* in_sizes, int n_in,
                              void* d_out, int out_size, void* d_ws, size_t ws_size,
                              hipStream_t stream) {
    const float* imgs    = (const float*)d_in[0];
    const float* depths  = (const float*)d_in[1];
    const float* poses   = (const float*)d_in[2];
    const float* intr    = (const float*)d_in[3];
    const float* patch_w = (const float*)d_in[5];
    const float* patch_b = (const float*)d_in[6];
    const float* cls_tok = (const float*)d_in[7];
    const float* pos_emb = (const float*)d_in[8];
    const float* ln1_g   = (const float*)d_in[9];
    const float* ln1_b   = (const float*)d_in[10];
    const float* qkv_w   = (const float*)d_in[11];
    const float* qkv_b   = (const float*)d_in[12];
    const float* proj_w  = (const float*)d_in[13];
    const float* proj_b  = (const float*)d_in[14];
    const float* ln2_g   = (const float*)d_in[15];
    const float* ln2_b   = (const float*)d_in[16];
    const float* fc1_w   = (const float*)d_in[17];
    const float* fc1_b   = (const float*)d_in[18];
    const float* fc2_w   = (const float*)d_in[19];
    const float* fc2_b   = (const float*)d_in[20];
    const float* nf_g    = (const float*)d_in[21];
    const float* nf_b    = (const float*)d_in[22];
    const float* conv_w  = (const float*)d_in[23];
    const float* conv_b  = (const float*)d_in[24];
    float* out = (float*)d_out;
    float* ws  = (float*)d_ws;

    // ---- workspace layout (float-slot offsets) ----
    const size_t OFF_TOK  = 0;                    // fp32 [1576][768]
    const size_t OFF_FB   = 1210368;              // fp32 partials [4][1576][768] / patch tmp
    const size_t OFF_PB   = 6051840;              // qkv f16 | mlp bf16 | final-LN fp32
    const size_t OFF_HB   = 8472576;              // bf16 [1576][768]
    const size_t OFF_PT   = 9077760;              // bf16 patchT [768][768]
    const size_t OFF_SSUM = 9372672;
    const size_t OFF_SMAX = 9673728;
    const size_t OFF_CNT  = 9974784;
    const size_t OFF_IDX  = 9975296;
    const size_t OFF_W    = 9977344;              // bf16 12x7077888 (170 MB)

    float* tok  = ws + OFF_TOK;
    float* fbig = ws + OFF_FB;
    float* pbuf = ws + OFF_PB;
    _Float16* qkv_h = (_Float16*)pbuf;
    __hip_bfloat16* hb  = (__hip_bfloat16*)(ws + OFF_HB);
    __hip_bfloat16* pT  = (__hip_bfloat16*)(ws + OFF_PT);
    __hip_bfloat16* wbuf = (__hip_bfloat16*)(ws + OFF_W);
    float* ssum = ws + OFF_SSUM;
    float* smax = ws + OFF_SMAX;
    float* cnt  = ws + OFF_CNT;
    int*   idxb = (int*)(ws + OFF_IDX);

    const int MT = (NROWS + 63) / 64;     // 25
    const int MTP = (NPATCH + 63) / 64;   // 25

    // ---- all weight conversion in one dispatch ----
    convT_all<<<20880, 256, 0, stream>>>(qkv_w, proj_w, fc1_w, fc2_w, patch_w, wbuf, pT);

    // ---- patch embedding + layer-0 LN ----
    patch_extract_kernel<<<(NPATCH * DMODEL) / 256, 256, 0, stream>>>(imgs, hb);
    gemm_t<64, 64><<<dim3(12 * MTP, 1, 1), 256, 0, stream>>>(
        hb, pT, patch_b, nullptr, fbig, NPATCH, 768, 768, 0, 12, nullptr);
    assemble_ln_kernel<<<NROWS, 256, 0, stream>>>(
        fbig, cls_tok, pos_emb, ln1_g, ln1_b, tok, hb);

    // ---- transformer blocks (R6 tile config + counted-vmcnt pipeline) ----
    for (int l = 0; l < 12; l++) {
        __hip_bfloat16* wl  = wbuf + (size_t)l * 7077888;
        __hip_bfloat16* wq  = wl;
        __hip_bfloat16* wp  = wl + 1769472;
        __hip_bfloat16* wf1 = wl + 2359296;
        __hip_bfloat16* wf2 = wl + 4718592;

        gemm_t<64, 128><<<dim3(18 * MT, 1, 1), 256, 0, stream>>>(
            hb, wq, qkv_b + (size_t)l * 2304, nullptr, qkv_h, NROWS, 2304, 768,
            4 /*f16*/, 18, nullptr);
        fused_attn_kernel<<<dim3(NIMG * NHEADS, 4), 256, 0, stream>>>(qkv_h, hb);
        gemm_t<64, 64><<<dim3(12 * MT, 1, 2), 256, 0, stream>>>(
            hb, wp, nullptr, nullptr, nullptr, NROWS, 768, 768,
            8 /*partial*/, 12, fbig);
        redln_kernel<2, 0><<<NROWS, 256, 0, stream>>>(
            fbig, proj_b + (size_t)l * DMODEL, tok,
            ln2_g + l * DMODEL, ln2_b + l * DMODEL, hb, nullptr);
        gemm_t<64, 128><<<dim3(24 * MT, 1, 1), 256, 0, stream>>>(
            hb, wf1, fc1_b + (size_t)l * MLPD, nullptr, pbuf, NROWS, 3072, 768,
            3 /*gelu|bf16*/, 24, nullptr);
        gemm_t<64, 64><<<dim3(12 * MT, 1, 2), 256, 0, stream>>>(
            (__hip_bfloat16*)pbuf, wf2, nullptr, nullptr, nullptr, NROWS, 768, 3072,
            8 /*partial*/, 12, fbig);
        if (l < 11) {
            redln_kernel<2, 0><<<NROWS, 256, 0, stream>>>(
                fbig, fc2_b + (size_t)l * DMODEL, tok,
                ln1_g + (l + 1) * DMODEL, ln1_b + (l + 1) * DMODEL, hb, nullptr);
        } else {
            redln_kernel<2, 1><<<NROWS, 256, 0, stream>>>(
                fbig, fc2_b + (size_t)l * DMODEL, tok,
                nf_g, nf_b, nullptr, pbuf);
        }
    }

    // ---- BEV splat ----
    bev_index_kernel<<<NIMG, 256, 0, stream>>>(depths, poses, intr, idxb);
    hipMemsetAsync(ssum, 0, (2 * (size_t)NCELL * DMODEL + 512) * sizeof(float), stream);
    splat_kernel<<<NPATCH, 256, 0, stream>>>(pbuf, idxb, ssum, smax, cnt);

    // ---- bev combine + conv ----
    bev_conv_kernel<<<NCELL, 256, 0, stream>>>(ssum, smax, cnt, conv_w, conv_b, out);
}

// Round 10
// 1598.125 us; speedup vs baseline: 1.0174x; 1.0174x over previous
//
#include <hip/hip_runtime.h>
#include <hip/hip_bf16.h>
#include <math.h>
#include <type_traits>
#include <utility>

// ---------------- problem constants ----------------
#define DMODEL 768
#define NTOK 197
#define NIMG 8            // B*NV
#define NHEADS 12
#define MLPD 3072
#define NROWS (NIMG*NTOK)     // 1576
#define NPATCH (NIMG*196)     // 1568
#define HF 14
#define BATCH 2
#define NCELL (BATCH*HF*HF)   // 392
#define FD 256

typedef __attribute__((ext_vector_type(8))) short s8v;
typedef __attribute__((ext_vector_type(8))) __bf16 b8v;
typedef __attribute__((ext_vector_type(8))) _Float16 h8v;
typedef __attribute__((ext_vector_type(4))) float f32x4;

// ---- MFMA builtin operand-type pickers (vector elt type varies across ROCm) ----
template <typename V, typename = void>
struct mfma_takes : std::false_type {};
template <typename V>
struct mfma_takes<V, std::void_t<decltype(
    __builtin_amdgcn_mfma_f32_16x16x32_bf16(std::declval<V>(), std::declval<V>(),
                                            std::declval<f32x4>(), 0, 0, 0))>>
    : std::true_type {};

template <typename V>
struct MfmaCall {
    static __device__ inline f32x4 run(s8v a, s8v b, f32x4 c) {
        return __builtin_amdgcn_mfma_f32_16x16x32_bf16(
            __builtin_bit_cast(V, a), __builtin_bit_cast(V, b), c, 0, 0, 0);
    }
};
using mfma_v = std::conditional_t<mfma_takes<b8v>::value, b8v, s8v>;

template <typename V, typename = void>
struct mfma16_takes : std::false_type {};
template <typename V>
struct mfma16_takes<V, std::void_t<decltype(
    __builtin_amdgcn_mfma_f32_16x16x32_f16(std::declval<V>(), std::declval<V>(),
                                           std::declval<f32x4>(), 0, 0, 0))>>
    : std::true_type {};

template <typename V>
struct MfmaF16Call {
    static __device__ inline f32x4 run(s8v a, s8v b, f32x4 c) {
        return __builtin_amdgcn_mfma_f32_16x16x32_f16(
            __builtin_bit_cast(V, a), __builtin_bit_cast(V, b), c, 0, 0, 0);
    }
};
using mfma16_v = std::conditional_t<mfma16_takes<h8v>::value, h8v, s8v>;

typedef __attribute__((address_space(1))) const unsigned int guint_t;
typedef __attribute__((address_space(3))) unsigned int luint_t;

// ---------------- templated bf16 MFMA GEMM (2-phase prefetch dbuf, BK=64) ----------------
// C[M,N] = epilogue(A[M,K] @ B[K,N]), B supplied TRANSPOSED: BT[N][K].
// BK=64 (half the barriers of BK=32), 4 waves 2x2, wave tile (BM/2)x(BN/2),
// global_load_lds staging, double-buffered LDS, prefetch overlaps MFMA.
// flags: bit0=GELU, bit1=bf16 out, bit2=f16 out, bit3=raw fp32 partial
// grid: x = nx*ny flattened (XCD-swizzled), z = split-K index; K % (64*S) == 0
template <int BM, int BN>
__global__ __launch_bounds__(256) void gemm_t(
    const __hip_bfloat16* __restrict__ A, const __hip_bfloat16* __restrict__ BT,
    const float* __restrict__ bias, const float* __restrict__ res,
    void* __restrict__ Cout, int M, int N, int K, int flags, int nx,
    float* __restrict__ part)
{
    constexpr int FM = BM / 32;
    constexpr int FN = BN / 32;
    __shared__ short Asl[2][BM * 64];
    __shared__ short Bsl[2][BN * 64];
    int t = threadIdx.x;
    int w = t >> 6, lane = t & 63;

    // bijective XCD swizzle (m204)
    int nwg = gridDim.x;
    int id = blockIdx.x;
    int q = nwg >> 3, r = nwg & 7;
    int xcd = id & 7;
    int wgid = (xcd < r ? xcd * (q + 1) : r * (q + 1) + (xcd - r) * q) + (id >> 3);
    int bx = wgid % nx, by = wgid / nx;
    int bm = by * BM, bn = bx * BN;

    int S = gridDim.z, z = blockIdx.z;
    int kchunk = K / S;
    int kbeg = z * kchunk;
    int nk = kchunk >> 6;

    int rbase = (w >> 1) * (BM / 2), cbase = (w & 1) * (BN / 2);

    f32x4 acc[FM][FN];
    #pragma unroll
    for (int i = 0; i < FM; i++)
        #pragma unroll
        for (int j = 0; j < FN; j++)
            acc[i][j] = (f32x4){0.f, 0.f, 0.f, 0.f};

    const short* Ag = (const short*)A;
    const short* Bg = (const short*)BT;

    auto STAGE = [&](int buf, int k0) {
        #pragma unroll
        for (int i = 0; i < BM * 8 / 256; i++) {
            int c = i * 256 + t;
            int row = c >> 3, koff = (c & 7) * 8;
            int ga = bm + row; if (ga >= M) ga = M - 1;
            __builtin_amdgcn_global_load_lds(
                (guint_t*)(Ag + (size_t)ga * K + k0 + koff),
                (luint_t*)(&Asl[buf][0] + c * 8), 16, 0, 0);
        }
        #pragma unroll
        for (int i = 0; i < BN * 8 / 256; i++) {
            int c = i * 256 + t;
            int row = c >> 3, koff = (c & 7) * 8;
            __builtin_amdgcn_global_load_lds(
                (guint_t*)(Bg + (size_t)(bn + row) * K + k0 + koff),
                (luint_t*)(&Bsl[buf][0] + c * 8), 16, 0, 0);
        }
    };

    STAGE(0, kbeg);
    int kk = (lane >> 4) * 8;
    int rl = lane & 15;

    for (int kt = 0; kt < nk; kt++) {
        int cur = kt & 1;
        __syncthreads();                       // drains prefetch vmcnt + prev reads
        if (kt + 1 < nk) STAGE(cur ^ 1, kbeg + (kt + 1) * 64);
        #pragma unroll
        for (int ks = 0; ks < 2; ks++) {
            s8v af[FM], bfr[FN];
            #pragma unroll
            for (int i = 0; i < FM; i++)
                af[i] = *(const s8v*)(&Asl[cur][0] + (rbase + i * 16 + rl) * 64 + ks * 32 + kk);
            #pragma unroll
            for (int j = 0; j < FN; j++)
                bfr[j] = *(const s8v*)(&Bsl[cur][0] + (cbase + j * 16 + rl) * 64 + ks * 32 + kk);
            #pragma unroll
            for (int i = 0; i < FM; i++)
                #pragma unroll
                for (int j = 0; j < FN; j++)
                    acc[i][j] = MfmaCall<mfma_v>::run(af[i], bfr[j], acc[i][j]);
        }
    }

    int colg = lane & 15;
    int rowg = (lane >> 4) * 4;
    #pragma unroll
    for (int i = 0; i < FM; i++) {
        #pragma unroll
        for (int j = 0; j < FN; j++) {
            #pragma unroll
            for (int qq = 0; qq < 4; qq++) {
                int rr = bm + rbase + i * 16 + rowg + qq;
                int cc = bn + cbase + j * 16 + colg;
                if (rr < M) {
                    float v = acc[i][j][qq];
                    if (flags & 8) {
                        part[((size_t)z * M + rr) * N + cc] = v;
                    } else {
                        if (bias) v += bias[cc];
                        if (flags & 1) v = 0.5f * v * (1.0f + erff(v * 0.7071067811865476f));
                        if (res)  v += res[(size_t)rr * N + cc];
                        if (flags & 2)
                            ((__hip_bfloat16*)Cout)[(size_t)rr * N + cc] = __float2bfloat16(v);
                        else if (flags & 4)
                            ((_Float16*)Cout)[(size_t)rr * N + cc] = (_Float16)v;
                        else
                            ((float*)Cout)[(size_t)rr * N + cc] = v;
                    }
                }
            }
        }
    }
}

// ---------------- fused reduce + LayerNorm ----------------
// tok' = tok + sum(part[0..NPART)) + bias ; h = LN(tok') -> bf16 (or fp32 final)
template <int NPART, int FINAL>
__global__ __launch_bounds__(256) void redln_kernel(
    const float* __restrict__ part, const float* __restrict__ bias,
    float* __restrict__ tok, const float* __restrict__ g,
    const float* __restrict__ b, __hip_bfloat16* __restrict__ hout,
    float* __restrict__ fout)
{
    int r = blockIdx.x, t = threadIdx.x;
    __shared__ float red[8];
    float v[3];
    #pragma unroll
    for (int i = 0; i < 3; i++) {
        int idx = t + i * 256;
        float x = tok[(size_t)r * DMODEL + idx] + bias[idx];
        #pragma unroll
        for (int p = 0; p < NPART; p++)
            x += part[((size_t)p * NROWS + r) * DMODEL + idx];
        v[i] = x;
        if (!FINAL) tok[(size_t)r * DMODEL + idx] = x;
    }
    float s = v[0] + v[1] + v[2];
    #pragma unroll
    for (int m = 32; m >= 1; m >>= 1) s += __shfl_xor(s, m);
    int wid = t >> 6, lane = t & 63;
    if (lane == 0) red[wid] = s;
    __syncthreads();
    float mean = (red[0] + red[1] + red[2] + red[3]) * (1.0f / DMODEL);
    float d0 = v[0] - mean, d1 = v[1] - mean, d2 = v[2] - mean;
    float qv = d0 * d0 + d1 * d1 + d2 * d2;
    #pragma unroll
    for (int m = 32; m >= 1; m >>= 1) qv += __shfl_xor(qv, m);
    __syncthreads();
    if (lane == 0) red[4 + wid] = qv;
    __syncthreads();
    float var = (red[4] + red[5] + red[6] + red[7]) * (1.0f / DMODEL);
    float rs = 1.0f / sqrtf(var + 1e-6f);
    float dd[3] = {d0, d1, d2};
    #pragma unroll
    for (int i = 0; i < 3; i++) {
        int idx = t + i * 256;
        float y = dd[i] * rs * g[idx] + b[idx];
        if (FINAL) fout[(size_t)r * DMODEL + idx] = y;
        else       hout[(size_t)r * DMODEL + idx] = __float2bfloat16(y);
    }
}

// layer-0 entry: tok = assemble(cls/patch + pos); h = LN(tok)
__global__ __launch_bounds__(256) void assemble_ln_kernel(
    const float* __restrict__ tmp, const float* __restrict__ cls,
    const float* __restrict__ pos, const float* __restrict__ g,
    const float* __restrict__ b, float* __restrict__ tok,
    __hip_bfloat16* __restrict__ hout)
{
    int rr = blockIdx.x;
    int n = rr / NTOK, r = rr % NTOK;
    int t = threadIdx.x;
    __shared__ float red[8];
    float v[3];
    #pragma unroll
    for (int i = 0; i < 3; i++) {
        int idx = t + i * 256;
        float x = (r == 0) ? cls[idx]
                           : tmp[((size_t)n * 196 + r - 1) * DMODEL + idx];
        x += pos[(size_t)r * DMODEL + idx];
        v[i] = x;
        tok[(size_t)rr * DMODEL + idx] = x;
    }
    float s = v[0] + v[1] + v[2];
    #pragma unroll
    for (int m = 32; m >= 1; m >>= 1) s += __shfl_xor(s, m);
    int wid = t >> 6, lane = t & 63;
    if (lane == 0) red[wid] = s;
    __syncthreads();
    float mean = (red[0] + red[1] + red[2] + red[3]) * (1.0f / DMODEL);
    float d0 = v[0] - mean, d1 = v[1] - mean, d2 = v[2] - mean;
    float qv = d0 * d0 + d1 * d1 + d2 * d2;
    #pragma unroll
    for (int m = 32; m >= 1; m >>= 1) qv += __shfl_xor(qv, m);
    __syncthreads();
    if (lane == 0) red[4 + wid] = qv;
    __syncthreads();
    float var = (red[4] + red[5] + red[6] + red[7]) * (1.0f / DMODEL);
    float rs = 1.0f / sqrtf(var + 1e-6f);
    float dd[3] = {d0, d1, d2};
    #pragma unroll
    for (int i = 0; i < 3; i++) {
        int idx = t + i * 256;
        hout[(size_t)rr * DMODEL + idx] = __float2bfloat16(dd[i] * rs * g[idx] + b[idx]);
    }
}

// ---------------- fused attention (f16 MFMA, 64-row q blocks, 2 blocks/CU) ----
#define AT_STR 232     // P / Vt row stride in f16
#define KS_STR 72      // Q / K row stride in f16

__global__ __launch_bounds__(256) void fused_attn_kernel(
    const _Float16* __restrict__ qkv, __hip_bfloat16* __restrict__ O)
{
    __shared__ char smem[29696 + 39168];              // 67.25 KB -> 2 blocks/CU
    _Float16* Vt = (_Float16*)smem;                   // [64][232]
    _Float16* Qs = (_Float16*)(smem + 29696);         // [64][72]
    _Float16* Ks = Qs + 64 * KS_STR;                  // [208][72]
    _Float16* Pl = (_Float16*)(smem + 29696);         // alias: [64][232]

    int nh = blockIdx.x;            // 0..95
    int n = nh / NHEADS, hh = nh % NHEADS;
    int qoff = blockIdx.y * 64;
    int t = threadIdx.x;
    int w = t >> 6, lane = t & 63;
    int g = lane >> 4, rl = lane & 15;
    const _Float16* base = qkv + (size_t)n * NTOK * 2304;

    // ---- stage K (rows >=197 zeroed), Q (clamped), V^T ----
    for (int idx = t; idx < 208 * 8; idx += 256) {
        int row = idx >> 3, c8 = (idx & 7) * 8;
        if (row < NTOK)
            *(uint4*)(Ks + row * KS_STR + c8) =
                *(const uint4*)(base + (size_t)row * 2304 + 768 + hh * 64 + c8);
        else
            *(uint4*)(Ks + row * KS_STR + c8) = make_uint4(0, 0, 0, 0);
    }
    for (int idx = t; idx < 64 * 8; idx += 256) {
        int row = idx >> 3, c8 = (idx & 7) * 8;
        int gq = qoff + row; if (gq > NTOK - 1) gq = NTOK - 1;
        *(uint4*)(Qs + row * KS_STR + c8) =
            *(const uint4*)(base + (size_t)gq * 2304 + hh * 64 + c8);
    }
    for (int idx = t; idx < NTOK * 8; idx += 256) {
        int k = idx >> 3, dg = (idx & 7) * 8;
        _Float16 tmp[8];
        *(uint4*)tmp = *(const uint4*)(base + (size_t)k * 2304 + 1536 + hh * 64 + dg);
        #pragma unroll
        for (int j = 0; j < 8; j++) Vt[(dg + j) * AT_STR + k] = tmp[j];
    }
    for (int idx = t; idx < 64 * 27; idx += 256) {     // zero Vt cols 197..223
        int d = idx / 27, k = NTOK + idx % 27;
        Vt[d * AT_STR + k] = (_Float16)0.f;
    }
    __syncthreads();

    // ---- S = Q K^T : wave handles 16 q rows x 13 k-tiles ----
    int wq0 = w * 16;
    f32x4 sacc[13];
    #pragma unroll
    for (int tt = 0; tt < 13; tt++) sacc[tt] = (f32x4){0.f, 0.f, 0.f, 0.f};

    __builtin_amdgcn_s_setprio(1);
    #pragma unroll
    for (int s = 0; s < 2; s++) {
        s8v af = *(const s8v*)(Qs + (wq0 + rl) * KS_STR + s * 32 + 8 * g);
        #pragma unroll
        for (int tt = 0; tt < 13; tt++) {
            s8v bf = *(const s8v*)(Ks + (tt * 16 + rl) * KS_STR + s * 32 + 8 * g);
            sacc[tt] = MfmaF16Call<mfma16_v>::run(af, bf, sacc[tt]);
        }
    }
    __builtin_amdgcn_s_setprio(0);
    __syncthreads();   // all waves done reading Qs/Ks before P overwrites

    // ---- softmax (lane holds col=rl+16*tt for row g*4+r) ----
    _Float16* Pw = Pl + wq0 * AT_STR;
    #pragma unroll
    for (int r = 0; r < 4; r++) {
        float vv[13];
        float mx = -3.0e38f;
        #pragma unroll
        for (int tt = 0; tt < 13; tt++) {
            float v = sacc[tt][r] * 0.125f;
            vv[tt] = v;
            if (rl + 16 * tt < NTOK) mx = fmaxf(mx, v);
        }
        mx = fmaxf(mx, __shfl_xor(mx, 1));
        mx = fmaxf(mx, __shfl_xor(mx, 2));
        mx = fmaxf(mx, __shfl_xor(mx, 4));
        mx = fmaxf(mx, __shfl_xor(mx, 8));
        float pv[13];
        float sum = 0.f;
        #pragma unroll
        for (int tt = 0; tt < 13; tt++) {
            float p = (rl + 16 * tt < NTOK) ? __expf(vv[tt] - mx) : 0.f;
            pv[tt] = p; sum += p;
        }
        sum += __shfl_xor(sum, 1);
        sum += __shfl_xor(sum, 2);
        sum += __shfl_xor(sum, 4);
        sum += __shfl_xor(sum, 8);
        float rinv = 1.0f / sum;
        int prow = g * 4 + r;
        #pragma unroll
        for (int tt = 0; tt < 13; tt++)
            Pw[prow * AT_STR + rl + 16 * tt] = (_Float16)(pv[tt] * rinv);
    }
    for (int idx = lane; idx < 16 * 16; idx += 64) {   // zero P cols 208..223
        int rr = idx >> 4, cc = 208 + (idx & 15);
        Pw[rr * AT_STR + cc] = (_Float16)0.f;
    }
    // no barrier: each wave reads only its own Pw region + stable Vt

    // ---- O = P V : 4 n-tiles, 7 k-steps ----
    f32x4 oacc[4];
    #pragma unroll
    for (int j = 0; j < 4; j++) oacc[j] = (f32x4){0.f, 0.f, 0.f, 0.f};

    __builtin_amdgcn_s_setprio(1);
    for (int s = 0; s < 7; s++) {
        s8v pf = *(const s8v*)(Pw + rl * AT_STR + s * 32 + 8 * g);
        s8v vf[4];
        #pragma unroll
        for (int j = 0; j < 4; j++)
            vf[j] = *(const s8v*)(Vt + (j * 16 + rl) * AT_STR + s * 32 + 8 * g);
        #pragma unroll
        for (int j = 0; j < 4; j++)
            oacc[j] = MfmaF16Call<mfma16_v>::run(pf, vf[j], oacc[j]);
    }
    __builtin_amdgcn_s_setprio(0);

    #pragma unroll
    for (int j = 0; j < 4; j++) {
        #pragma unroll
        for (int r = 0; r < 4; r++) {
            int qidx = qoff + wq0 + g * 4 + r;
            if (qidx < NTOK) {
                int d = j * 16 + rl;
                O[((size_t)n * NTOK + qidx) * DMODEL + hh * 64 + d] =
                    __float2bfloat16(oacc[j][r]);
            }
        }
    }
}

// ---------------- weight convert + transpose (fp32 [K][N] -> bf16 [N][K]) ----
// 32K x 128N tile: 512B coalesced fp32 reads/row, conflict-free LDS, 32B writes.
__device__ inline void transpose_tile_wide(const float* __restrict__ src,
                                           __hip_bfloat16* __restrict__ dst,
                                           int K, int N, int b)
{
    __shared__ float tl[32][129];
    int ntn = N >> 7;
    int n0 = (b % ntn) * 128, k0 = (b / ntn) * 32;
    int t = threadIdx.x;
    #pragma unroll
    for (int i = 0; i < 16; i++) {
        int idx = i * 256 + t;
        int kk = idx >> 7, nn = idx & 127;
        tl[kk][nn] = src[(size_t)(k0 + kk) * N + n0 + nn];
    }
    __syncthreads();
    int n = t >> 1, kc = (t & 1) * 16;
    __hip_bfloat16 v[16];
    #pragma unroll
    for (int j = 0; j < 16; j++) v[j] = __float2bfloat16(tl[kc + j][n]);
    *(uint4*)(dst + (size_t)(n0 + n) * K + k0 + kc)     = *(uint4*)&v[0];
    *(uint4*)(dst + (size_t)(n0 + n) * K + k0 + kc + 8) = *(uint4*)&v[8];
}

// one dispatch: all 12 layers (qkv|proj|fc1|fc2) + patch_w
// per-layer tiles: qkv 432, proj 144, fc1 576, fc2 576 = 1728; patch 144
__global__ __launch_bounds__(256) void convT_all(
    const float* __restrict__ qkv_w, const float* __restrict__ proj_w,
    const float* __restrict__ fc1_w, const float* __restrict__ fc2_w,
    const float* __restrict__ patch_w,
    __hip_bfloat16* __restrict__ wbuf, __hip_bfloat16* __restrict__ patchT)
{
    int b = blockIdx.x;
    if (b < 20736) {
        int layer = b / 1728, rem = b % 1728;
        __hip_bfloat16* wl = wbuf + (size_t)layer * 7077888;
        const float* src; __hip_bfloat16* dst; int K, N, tb;
        if (rem < 432)       { tb = rem;        src = qkv_w  + (size_t)layer * 768 * 2304; dst = wl;           K = 768;  N = 2304; }
        else if (rem < 576)  { tb = rem - 432;  src = proj_w + (size_t)layer * 768 * 768;  dst = wl + 1769472; K = 768;  N = 768;  }
        else if (rem < 1152) { tb = rem - 576;  src = fc1_w  + (size_t)layer * 768 * 3072; dst = wl + 2359296; K = 768;  N = 3072; }
        else                 { tb = rem - 1152; src = fc2_w  + (size_t)layer * 3072 * 768; dst = wl + 4718592; K = 3072; N = 768;  }
        transpose_tile_wide(src, dst, K, N, tb);
    } else {
        transpose_tile_wide(patch_w, patchT, 768, 768, b - 20736);
    }
}

// ---------------- patch extraction (fp32 img -> bf16 patch matrix) ----------------
__global__ __launch_bounds__(256) void patch_extract_kernel(
    const float* __restrict__ img, __hip_bfloat16* __restrict__ Pm)
{
    size_t e = (size_t)blockIdx.x * 256 + threadIdx.x;
    if (e >= (size_t)NPATCH * DMODEL) return;
    int cidx = (int)(e % DMODEL);
    int r    = (int)(e / DMODEL);
    int n  = r / 196, s = r % 196;
    int hi = s / HF, wi = s % HF;
    int c  = cidx >> 8, py = (cidx >> 4) & 15, px = cidx & 15;
    Pm[e] = __float2bfloat16(
        img[(((size_t)n * 3 + c) * 224 + hi * 16 + py) * 224 + wi * 16 + px]);
}

// ---------------- 4x4 inverse (adjugate) ----------------
__device__ void invert4(const float m[16], float out[16]) {
    float inv[16];
    inv[0] = m[5]*m[10]*m[15] - m[5]*m[11]*m[14] - m[9]*m[6]*m[15] + m[9]*m[7]*m[14] + m[13]*m[6]*m[11] - m[13]*m[7]*m[10];
    inv[4] = -m[4]*m[10]*m[15] + m[4]*m[11]*m[14] + m[8]*m[6]*m[15] - m[8]*m[7]*m[14] - m[12]*m[6]*m[11] + m[12]*m[7]*m[10];
    inv[8] = m[4]*m[9]*m[15] - m[4]*m[11]*m[13] - m[8]*m[5]*m[15] + m[8]*m[7]*m[13] + m[12]*m[5]*m[11] - m[12]*m[7]*m[9];
    inv[12] = -m[4]*m[9]*m[14] + m[4]*m[10]*m[13] + m[8]*m[5]*m[14] - m[8]*m[6]*m[13] - m[12]*m[5]*m[10] + m[12]*m[6]*m[9];
    inv[1] = -m[1]*m[10]*m[15] + m[1]*m[11]*m[14] + m[9]*m[2]*m[15] - m[9]*m[3]*m[14] - m[13]*m[2]*m[11] + m[13]*m[3]*m[10];
    inv[5] = m[0]*m[10]*m[15] - m[0]*m[11]*m[14] - m[8]*m[2]*m[15] + m[8]*m[3]*m[14] + m[12]*m[2]*m[11] - m[12]*m[3]*m[10];
    inv[9] = -m[0]*m[9]*m[15] + m[0]*m[11]*m[13] + m[8]*m[1]*m[15] - m[8]*m[3]*m[13] - m[12]*m[1]*m[11] + m[12]*m[3]*m[9];
    inv[13] = m[0]*m[9]*m[14] - m[0]*m[10]*m[13] - m[8]*m[1]*m[14] + m[8]*m[2]*m[13] + m[12]*m[1]*m[10] - m[12]*m[2]*m[9];
    inv[2] = m[1]*m[6]*m[15] - m[1]*m[7]*m[14] - m[5]*m[2]*m[15] + m[5]*m[3]*m[14] + m[13]*m[2]*m[7] - m[13]*m[3]*m[6];
    inv[6] = -m[0]*m[6]*m[15] + m[0]*m[7]*m[14] + m[4]*m[2]*m[15] - m[4]*m[3]*m[14] - m[12]*m[2]*m[7] + m[12]*m[3]*m[6];
    inv[10] = m[0]*m[5]*m[15] - m[0]*m[7]*m[13] - m[4]*m[1]*m[15] + m[4]*m[3]*m[13] + m[12]*m[1]*m[7] - m[12]*m[3]*m[5];
    inv[14] = -m[0]*m[5]*m[14] + m[0]*m[6]*m[13] + m[4]*m[1]*m[14] - m[4]*m[2]*m[13] - m[12]*m[1]*m[6] + m[12]*m[2]*m[5];
    inv[3] = -m[1]*m[6]*m[11] + m[1]*m[7]*m[10] + m[5]*m[2]*m[11] - m[5]*m[3]*m[10] - m[9]*m[2]*m[7] + m[9]*m[3]*m[6];
    inv[7] = m[0]*m[6]*m[11] - m[0]*m[7]*m[10] - m[4]*m[2]*m[11] + m[4]*m[3]*m[10] + m[8]*m[2]*m[7] - m[8]*m[3]*m[6];
    inv[11] = -m[0]*m[5]*m[11] + m[0]*m[7]*m[9] + m[4]*m[1]*m[11] - m[4]*m[3]*m[9] - m[8]*m[1]*m[7] + m[8]*m[3]*m[5];
    inv[15] = m[0]*m[5]*m[10] - m[0]*m[6]*m[9] - m[4]*m[1]*m[10] + m[4]*m[2]*m[9] + m[8]*m[1]*m[6] - m[8]*m[2]*m[5];
    float det = m[0]*inv[0] + m[1]*inv[4] + m[2]*inv[8] + m[3]*inv[12];
    det = 1.0f / det;
    for (int i = 0; i < 16; i++) out[i] = inv[i] * det;
}

// ---------------- BEV index / validity ----------------
__global__ __launch_bounds__(256) void bev_index_kernel(
    const float* __restrict__ depths, const float* __restrict__ poses,
    const float* __restrict__ intr, int* __restrict__ idxbuf)
{
    int bv = blockIdx.x;          // 0..7
    int b  = bv / 4;
    __shared__ float c2w[16];
    if (threadIdx.x == 0) {
        float w2c[16];
        const float* Pm = poses + bv * 16;
        const int perm[4] = {1, 0, 2, 3};
        for (int i = 0; i < 4; i++)
            for (int j = 0; j < 4; j++)
                w2c[i * 4 + j] = Pm[perm[i] * 4 + j];
        invert4(w2c, c2w);
    }
    __syncthreads();
    int t = threadIdx.x;
    if (t >= 196) return;
    int hh = t / HF, ww = t % HF;
    const float* dp = depths + (size_t)bv * 224 * 224;
    int r0 = hh * 16 + 7, c0 = ww * 16 + 7;
    float d = 0.25f * (dp[r0 * 224 + c0] + dp[r0 * 224 + c0 + 1] +
                       dp[(r0 + 1) * 224 + c0] + dp[(r0 + 1) * 224 + c0 + 1]);
    d *= 65.535f;
    bool mask = (d > 0.0f) && (d < 5.0f);
    float fx = intr[bv * 9 + 0], fy = intr[bv * 9 + 4];
    float cx = intr[bv * 9 + 2], cy = intr[bv * 9 + 5];
    float u = (float)ww, v = (float)hh;
    float Xc = -((u - cx) * d / (fx + 1e-8f));
    float Yc = (v - cy) * d / (fy + 1e-8f);
    float Xw = c2w[0] * Xc + c2w[1] * Yc + c2w[2] * d + c2w[3];
    float Yw = c2w[4] * Xc + c2w[5] * Yc + c2w[6] * d + c2w[7];
    float px = Xw * 1.4f + 7.0f;
    float py = -(Yw * 1.4f) + 7.0f;
    int pxi = (int)rintf(px);
    int pyi = (int)rintf(py);
    bool inb = (pxi >= 0) && (pxi < HF) && (pyi >= 0) && (pyi < HF);
    idxbuf[bv * 196 + t] = (mask && inb) ? (b * 196 + pyi * HF + pxi) : -1;
}

// ---------------- scatter (segment sum / count / max) ----------------
__global__ __launch_bounds__(256) void splat_kernel(
    const float* __restrict__ src, const int* __restrict__ idxbuf,
    float* __restrict__ ssum, float* __restrict__ smax, float* __restrict__ cnt)
{
    int r = blockIdx.x;              // 0..1567
    int idx = idxbuf[r];
    if (idx < 0) return;
    int bv = r / 196, s = r % 196;
    const float* row = src + ((size_t)bv * NTOK + 1 + s) * DMODEL;
    int t = threadIdx.x;
    for (int d = t; d < DMODEL; d += 256) {
        float v = row[d];
        atomicAdd(&ssum[(size_t)idx * DMODEL + d], v);
        atomicMax((int*)(smax + (size_t)idx * DMODEL + d), __float_as_int(v));
    }
    if (t == 0) atomicAdd(&cnt[idx], 1.0f);
}

// ---------------- bev combine + 1x1 conv ----------------
__global__ __launch_bounds__(256) void bev_conv_kernel(
    const float* __restrict__ ssum, const float* __restrict__ smax,
    const float* __restrict__ cnt, const float* __restrict__ convw,
    const float* __restrict__ convb, float* __restrict__ out)
{
    int cell = blockIdx.x;           // 0..391
    __shared__ float bev[DMODEL];
    int t = threadIdx.x;
    float c = cnt[cell];
    for (int d = t; d < DMODEL; d += 256)
        bev[d] = 0.5f * (ssum[(size_t)cell * DMODEL + d] / (c + 1e-8f) +
                         smax[(size_t)cell * DMODEL + d]);
    __syncthreads();
    float acc = convb[t];
    const float4* wr = (const float4*)(convw + (size_t)t * DMODEL);
    #pragma unroll 4
    for (int dc = 0; dc < DMODEL / 4; dc++) {
        float4 w4 = wr[dc];
        acc += bev[dc * 4 + 0] * w4.x + bev[dc * 4 + 1] * w4.y +
               bev[dc * 4 + 2] * w4.z + bev[dc * 4 + 3] * w4.w;
    }
    int b = cell / 196, s = cell % 196;
    out[((size_t)b * FD + t) * 196 + s] = acc;
}

// ---------------- host launcher ----------------
extern "C" void kernel_launch(void* const* d_in, const int* in_sizes, int n_in,
                              void* d_out, int out_size, void* d_ws, size_t ws_size,
                              hipStream_t stream) {
    const float* imgs    = (const float*)d_in[0];
    const float* depths  = (const float*)d_in[1];
    const float* poses   = (const float*)d_in[2];
    const float* intr    = (const float*)d_in[3];
    const float* patch_w = (const float*)d_in[5];
    const float* patch_b = (const float*)d_in[6];
    const float* cls_tok = (const float*)d_in[7];
    const float* pos_emb = (const float*)d_in[8];
    const float* ln1_g   = (const float*)d_in[9];
    const float* ln1_b   = (const float*)d_in[10];
    const float* qkv_w   = (const float*)d_in[11];
    const float* qkv_b   = (const float*)d_in[12];
    const float* proj_w  = (const float*)d_in[13];
    const float* proj_b  = (const float*)d_in[14];
    const float* ln2_g   = (const float*)d_in[15];
    const float* ln2_b   = (const float*)d_in[16];
    const float* fc1_w   = (const float*)d_in[17];
    const float* fc1_b   = (const float*)d_in[18];
    const float* fc2_w   = (const float*)d_in[19];
    const float* fc2_b   = (const float*)d_in[20];
    const float* nf_g    = (const float*)d_in[21];
    const float* nf_b    = (const float*)d_in[22];
    const float* conv_w  = (const float*)d_in[23];
    const float* conv_b  = (const float*)d_in[24];
    float* out = (float*)d_out;
    float* ws  = (float*)d_ws;

    // ---- workspace layout (float-slot offsets) ----
    const size_t OFF_TOK  = 0;                    // fp32 [1576][768]
    const size_t OFF_FB   = 1210368;              // fp32 partials [4][1576][768] / patch tmp
    const size_t OFF_PB   = 6051840;              // qkv f16 | mlp bf16 | final-LN fp32
    const size_t OFF_HB   = 8472576;              // bf16 [1576][768]
    const size_t OFF_PT   = 9077760;              // bf16 patchT [768][768]
    const size_t OFF_SSUM = 9372672;
    const size_t OFF_SMAX = 9673728;
    const size_t OFF_CNT  = 9974784;
    const size_t OFF_IDX  = 9975296;
    const size_t OFF_W    = 9977344;              // bf16 12x7077888 (170 MB)

    float* tok  = ws + OFF_TOK;
    float* fbig = ws + OFF_FB;
    float* pbuf = ws + OFF_PB;
    _Float16* qkv_h = (_Float16*)pbuf;
    __hip_bfloat16* hb  = (__hip_bfloat16*)(ws + OFF_HB);
    __hip_bfloat16* pT  = (__hip_bfloat16*)(ws + OFF_PT);
    __hip_bfloat16* wbuf = (__hip_bfloat16*)(ws + OFF_W);
    float* ssum = ws + OFF_SSUM;
    float* smax = ws + OFF_SMAX;
    float* cnt  = ws + OFF_CNT;
    int*   idxb = (int*)(ws + OFF_IDX);

    const int MT = (NROWS + 63) / 64;     // 25
    const int MTP = (NPATCH + 63) / 64;   // 25

    // ---- all weight conversion in one dispatch ----
    convT_all<<<20880, 256, 0, stream>>>(qkv_w, proj_w, fc1_w, fc2_w, patch_w, wbuf, pT);

    // ---- patch embedding + layer-0 LN ----
    patch_extract_kernel<<<(NPATCH * DMODEL) / 256, 256, 0, stream>>>(imgs, hb);
    gemm_t<64, 64><<<dim3(12 * MTP, 1, 1), 256, 0, stream>>>(
        hb, pT, patch_b, nullptr, fbig, NPATCH, 768, 768, 0, 12, nullptr);
    assemble_ln_kernel<<<NROWS, 256, 0, stream>>>(
        fbig, cls_tok, pos_emb, ln1_g, ln1_b, tok, hb);

    // ---- transformer blocks (R6 tiles, BK=64 dbuf) ----
    for (int l = 0; l < 12; l++) {
        __hip_bfloat16* wl  = wbuf + (size_t)l * 7077888;
        __hip_bfloat16* wq  = wl;
        __hip_bfloat16* wp  = wl + 1769472;
        __hip_bfloat16* wf1 = wl + 2359296;
        __hip_bfloat16* wf2 = wl + 4718592;

        gemm_t<64, 128><<<dim3(18 * MT, 1, 1), 256, 0, stream>>>(
            hb, wq, qkv_b + (size_t)l * 2304, nullptr, qkv_h, NROWS, 2304, 768,
            4 /*f16*/, 18, nullptr);
        fused_attn_kernel<<<dim3(NIMG * NHEADS, 4), 256, 0, stream>>>(qkv_h, hb);
        gemm_t<64, 64><<<dim3(12 * MT, 1, 2), 256, 0, stream>>>(
            hb, wp, nullptr, nullptr, nullptr, NROWS, 768, 768,
            8 /*partial*/, 12, fbig);
        redln_kernel<2, 0><<<NROWS, 256, 0, stream>>>(
            fbig, proj_b + (size_t)l * DMODEL, tok,
            ln2_g + l * DMODEL, ln2_b + l * DMODEL, hb, nullptr);
        gemm_t<64, 128><<<dim3(24 * MT, 1, 1), 256, 0, stream>>>(
            hb, wf1, fc1_b + (size_t)l * MLPD, nullptr, pbuf, NROWS, 3072, 768,
            3 /*gelu|bf16*/, 24, nullptr);
        gemm_t<64, 64><<<dim3(12 * MT, 1, 2), 256, 0, stream>>>(
            (__hip_bfloat16*)pbuf, wf2, nullptr, nullptr, nullptr, NROWS, 768, 3072,
            8 /*partial*/, 12, fbig);
        if (l < 11) {
            redln_kernel<2, 0><<<NROWS, 256, 0, stream>>>(
                fbig, fc2_b + (size_t)l * DMODEL, tok,
                ln1_g + (l + 1) * DMODEL, ln1_b + (l + 1) * DMODEL, hb, nullptr);
        } else {
            redln_kernel<2, 1><<<NROWS, 256, 0, stream>>>(
                fbig, fc2_b + (size_t)l * DMODEL, tok,
                nf_g, nf_b, nullptr, pbuf);
        }
    }

    // ---- BEV splat ----
    bev_index_kernel<<<NIMG, 256, 0, stream>>>(depths, poses, intr, idxb);
    hipMemsetAsync(ssum, 0, (2 * (size_t)NCELL * DMODEL + 512) * sizeof(float), stream);
    splat_kernel<<<NPATCH, 256, 0, stream>>>(pbuf, idxb, ssum, smax, cnt);

    // ---- bev combine + conv ----
    bev_conv_kernel<<<NCELL, 256, 0, stream>>>(ssum, smax, cnt, conv_w, conv_b, out);
}

// Round 11
// 1553.899 us; speedup vs baseline: 1.0464x; 1.0285x over previous
//
#include <hip/hip_runtime.h>
#include <hip/hip_bf16.h>
#include <math.h>
#include <type_traits>
#include <utility>

// ---------------- problem constants ----------------
#define DMODEL 768
#define NTOK 197
#define NIMG 8            // B*NV
#define NHEADS 12
#define MLPD 3072
#define NROWS (NIMG*NTOK)     // 1576
#define NPATCH (NIMG*196)     // 1568
#define HF 14
#define BATCH 2
#define NCELL (BATCH*HF*HF)   // 392
#define FD 256

typedef __attribute__((ext_vector_type(8))) short s8v;
typedef __attribute__((ext_vector_type(8))) __bf16 b8v;
typedef __attribute__((ext_vector_type(8))) _Float16 h8v;
typedef __attribute__((ext_vector_type(4))) float f32x4;

// ---- MFMA builtin operand-type pickers (vector elt type varies across ROCm) ----
template <typename V, typename = void>
struct mfma_takes : std::false_type {};
template <typename V>
struct mfma_takes<V, std::void_t<decltype(
    __builtin_amdgcn_mfma_f32_16x16x32_bf16(std::declval<V>(), std::declval<V>(),
                                            std::declval<f32x4>(), 0, 0, 0))>>
    : std::true_type {};

template <typename V>
struct MfmaCall {
    static __device__ inline f32x4 run(s8v a, s8v b, f32x4 c) {
        return __builtin_amdgcn_mfma_f32_16x16x32_bf16(
            __builtin_bit_cast(V, a), __builtin_bit_cast(V, b), c, 0, 0, 0);
    }
};
using mfma_v = std::conditional_t<mfma_takes<b8v>::value, b8v, s8v>;

template <typename V, typename = void>
struct mfma16_takes : std::false_type {};
template <typename V>
struct mfma16_takes<V, std::void_t<decltype(
    __builtin_amdgcn_mfma_f32_16x16x32_f16(std::declval<V>(), std::declval<V>(),
                                           std::declval<f32x4>(), 0, 0, 0))>>
    : std::true_type {};

template <typename V>
struct MfmaF16Call {
    static __device__ inline f32x4 run(s8v a, s8v b, f32x4 c) {
        return __builtin_amdgcn_mfma_f32_16x16x32_f16(
            __builtin_bit_cast(V, a), __builtin_bit_cast(V, b), c, 0, 0, 0);
    }
};
using mfma16_v = std::conditional_t<mfma16_takes<h8v>::value, h8v, s8v>;

typedef __attribute__((address_space(1))) const unsigned int guint_t;
typedef __attribute__((address_space(3))) unsigned int luint_t;

// ---------------- templated bf16 MFMA GEMM (2-phase prefetch dbuf, BK=32) ----------------
// C[M,N] = epilogue(A[M,K] @ B[K,N]), B supplied TRANSPOSED: BT[N][K].
// BK=32, 4 waves 2x2, wave tile (BM/2)x(BN/2), global_load_lds staging,
// double-buffered LDS with next-tile prefetch overlapping MFMA (R8-proven).
// flags: bit0=GELU, bit1=bf16 out, bit2=f16 out, bit3=raw fp32 partial
// grid: x = nx*ny flattened (XCD-swizzled), z = split-K index
template <int BM, int BN>
__global__ __launch_bounds__(256) void gemm_t(
    const __hip_bfloat16* __restrict__ A, const __hip_bfloat16* __restrict__ BT,
    const float* __restrict__ bias, const float* __restrict__ res,
    void* __restrict__ Cout, int M, int N, int K, int flags, int nx,
    float* __restrict__ part)
{
    constexpr int FM = BM / 32;
    constexpr int FN = BN / 32;
    __shared__ short Asl[2][BM * 32];
    __shared__ short Bsl[2][BN * 32];
    int t = threadIdx.x;
    int w = t >> 6, lane = t & 63;

    // bijective XCD swizzle (m204)
    int nwg = gridDim.x;
    int id = blockIdx.x;
    int q = nwg >> 3, r = nwg & 7;
    int xcd = id & 7;
    int wgid = (xcd < r ? xcd * (q + 1) : r * (q + 1) + (xcd - r) * q) + (id >> 3);
    int bx = wgid % nx, by = wgid / nx;
    int bm = by * BM, bn = bx * BN;

    int S = gridDim.z, z = blockIdx.z;
    int kchunk = K / S;
    int kbeg = z * kchunk;
    int nk = kchunk >> 5;

    int rbase = (w >> 1) * (BM / 2), cbase = (w & 1) * (BN / 2);

    f32x4 acc[FM][FN];
    #pragma unroll
    for (int i = 0; i < FM; i++)
        #pragma unroll
        for (int j = 0; j < FN; j++)
            acc[i][j] = (f32x4){0.f, 0.f, 0.f, 0.f};

    const short* Ag = (const short*)A;
    const short* Bg = (const short*)BT;

    auto STAGE = [&](int buf, int k0) {
        #pragma unroll
        for (int i = 0; i < BM * 4 / 256; i++) {
            int c = i * 256 + t;
            int row = c >> 2, koff = (c & 3) * 8;
            int ga = bm + row; if (ga >= M) ga = M - 1;
            __builtin_amdgcn_global_load_lds(
                (guint_t*)(Ag + (size_t)ga * K + k0 + koff),
                (luint_t*)(&Asl[buf][0] + c * 8), 16, 0, 0);
        }
        #pragma unroll
        for (int i = 0; i < BN * 4 / 256; i++) {
            int c = i * 256 + t;
            int row = c >> 2, koff = (c & 3) * 8;
            __builtin_amdgcn_global_load_lds(
                (guint_t*)(Bg + (size_t)(bn + row) * K + k0 + koff),
                (luint_t*)(&Bsl[buf][0] + c * 8), 16, 0, 0);
        }
    };

    STAGE(0, kbeg);
    int kk = (lane >> 4) * 8;
    int rl = lane & 15;

    for (int kt = 0; kt < nk; kt++) {
        int cur = kt & 1;
        __syncthreads();                       // drains prefetch vmcnt + prev reads
        if (kt + 1 < nk) STAGE(cur ^ 1, kbeg + (kt + 1) * 32);
        s8v af[FM], bfr[FN];
        #pragma unroll
        for (int i = 0; i < FM; i++)
            af[i] = *(const s8v*)(&Asl[cur][0] + (rbase + i * 16 + rl) * 32 + kk);
        #pragma unroll
        for (int j = 0; j < FN; j++)
            bfr[j] = *(const s8v*)(&Bsl[cur][0] + (cbase + j * 16 + rl) * 32 + kk);
        #pragma unroll
        for (int i = 0; i < FM; i++)
            #pragma unroll
            for (int j = 0; j < FN; j++)
                acc[i][j] = MfmaCall<mfma_v>::run(af[i], bfr[j], acc[i][j]);
    }

    int colg = lane & 15;
    int rowg = (lane >> 4) * 4;
    #pragma unroll
    for (int i = 0; i < FM; i++) {
        #pragma unroll
        for (int j = 0; j < FN; j++) {
            #pragma unroll
            for (int qq = 0; qq < 4; qq++) {
                int rr = bm + rbase + i * 16 + rowg + qq;
                int cc = bn + cbase + j * 16 + colg;
                if (rr < M) {
                    float v = acc[i][j][qq];
                    if (flags & 8) {
                        part[((size_t)z * M + rr) * N + cc] = v;
                    } else {
                        if (bias) v += bias[cc];
                        if (flags & 1) v = 0.5f * v * (1.0f + erff(v * 0.7071067811865476f));
                        if (res)  v += res[(size_t)rr * N + cc];
                        if (flags & 2)
                            ((__hip_bfloat16*)Cout)[(size_t)rr * N + cc] = __float2bfloat16(v);
                        else if (flags & 4)
                            ((_Float16*)Cout)[(size_t)rr * N + cc] = (_Float16)v;
                        else
                            ((float*)Cout)[(size_t)rr * N + cc] = v;
                    }
                }
            }
        }
    }
}

// ---------------- fused reduce + LayerNorm ----------------
// tok' = tok + sum(part[0..NPART)) + bias ; h = LN(tok') -> bf16 (or fp32 final)
template <int NPART, int FINAL>
__global__ __launch_bounds__(256) void redln_kernel(
    const float* __restrict__ part, const float* __restrict__ bias,
    float* __restrict__ tok, const float* __restrict__ g,
    const float* __restrict__ b, __hip_bfloat16* __restrict__ hout,
    float* __restrict__ fout)
{
    int r = blockIdx.x, t = threadIdx.x;
    __shared__ float red[8];
    float v[3];
    #pragma unroll
    for (int i = 0; i < 3; i++) {
        int idx = t + i * 256;
        float x = tok[(size_t)r * DMODEL + idx] + bias[idx];
        #pragma unroll
        for (int p = 0; p < NPART; p++)
            x += part[((size_t)p * NROWS + r) * DMODEL + idx];
        v[i] = x;
        if (!FINAL) tok[(size_t)r * DMODEL + idx] = x;
    }
    float s = v[0] + v[1] + v[2];
    #pragma unroll
    for (int m = 32; m >= 1; m >>= 1) s += __shfl_xor(s, m);
    int wid = t >> 6, lane = t & 63;
    if (lane == 0) red[wid] = s;
    __syncthreads();
    float mean = (red[0] + red[1] + red[2] + red[3]) * (1.0f / DMODEL);
    float d0 = v[0] - mean, d1 = v[1] - mean, d2 = v[2] - mean;
    float qv = d0 * d0 + d1 * d1 + d2 * d2;
    #pragma unroll
    for (int m = 32; m >= 1; m >>= 1) qv += __shfl_xor(qv, m);
    __syncthreads();
    if (lane == 0) red[4 + wid] = qv;
    __syncthreads();
    float var = (red[4] + red[5] + red[6] + red[7]) * (1.0f / DMODEL);
    float rs = 1.0f / sqrtf(var + 1e-6f);
    float dd[3] = {d0, d1, d2};
    #pragma unroll
    for (int i = 0; i < 3; i++) {
        int idx = t + i * 256;
        float y = dd[i] * rs * g[idx] + b[idx];
        if (FINAL) fout[(size_t)r * DMODEL + idx] = y;
        else       hout[(size_t)r * DMODEL + idx] = __float2bfloat16(y);
    }
}

// layer-0 entry: tok = assemble(cls/patch + pos); h = LN(tok)
__global__ __launch_bounds__(256) void assemble_ln_kernel(
    const float* __restrict__ tmp, const float* __restrict__ cls,
    const float* __restrict__ pos, const float* __restrict__ g,
    const float* __restrict__ b, float* __restrict__ tok,
    __hip_bfloat16* __restrict__ hout)
{
    int rr = blockIdx.x;
    int n = rr / NTOK, r = rr % NTOK;
    int t = threadIdx.x;
    __shared__ float red[8];
    float v[3];
    #pragma unroll
    for (int i = 0; i < 3; i++) {
        int idx = t + i * 256;
        float x = (r == 0) ? cls[idx]
                           : tmp[((size_t)n * 196 + r - 1) * DMODEL + idx];
        x += pos[(size_t)r * DMODEL + idx];
        v[i] = x;
        tok[(size_t)rr * DMODEL + idx] = x;
    }
    float s = v[0] + v[1] + v[2];
    #pragma unroll
    for (int m = 32; m >= 1; m >>= 1) s += __shfl_xor(s, m);
    int wid = t >> 6, lane = t & 63;
    if (lane == 0) red[wid] = s;
    __syncthreads();
    float mean = (red[0] + red[1] + red[2] + red[3]) * (1.0f / DMODEL);
    float d0 = v[0] - mean, d1 = v[1] - mean, d2 = v[2] - mean;
    float qv = d0 * d0 + d1 * d1 + d2 * d2;
    #pragma unroll
    for (int m = 32; m >= 1; m >>= 1) qv += __shfl_xor(qv, m);
    __syncthreads();
    if (lane == 0) red[4 + wid] = qv;
    __syncthreads();
    float var = (red[4] + red[5] + red[6] + red[7]) * (1.0f / DMODEL);
    float rs = 1.0f / sqrtf(var + 1e-6f);
    float dd[3] = {d0, d1, d2};
    #pragma unroll
    for (int i = 0; i < 3; i++) {
        int idx = t + i * 256;
        hout[(size_t)rr * DMODEL + idx] = __float2bfloat16(dd[i] * rs * g[idx] + b[idx]);
    }
}

// ---------------- fused attention (f16 MFMA, 64-row q blocks, 2 blocks/CU) ----
#define AT_STR 232     // P / Vt row stride in f16
#define KS_STR 72      // Q / K row stride in f16

__global__ __launch_bounds__(256) void fused_attn_kernel(
    const _Float16* __restrict__ qkv, __hip_bfloat16* __restrict__ O)
{
    __shared__ char smem[29696 + 39168];              // 67.25 KB -> 2 blocks/CU
    _Float16* Vt = (_Float16*)smem;                   // [64][232]
    _Float16* Qs = (_Float16*)(smem + 29696);         // [64][72]
    _Float16* Ks = Qs + 64 * KS_STR;                  // [208][72]
    _Float16* Pl = (_Float16*)(smem + 29696);         // alias: [64][232]

    int nh = blockIdx.x;            // 0..95
    int n = nh / NHEADS, hh = nh % NHEADS;
    int qoff = blockIdx.y * 64;
    int t = threadIdx.x;
    int w = t >> 6, lane = t & 63;
    int g = lane >> 4, rl = lane & 15;
    const _Float16* base = qkv + (size_t)n * NTOK * 2304;

    // ---- stage K (rows >=197 zeroed), Q (clamped), V^T ----
    for (int idx = t; idx < 208 * 8; idx += 256) {
        int row = idx >> 3, c8 = (idx & 7) * 8;
        if (row < NTOK)
            *(uint4*)(Ks + row * KS_STR + c8) =
                *(const uint4*)(base + (size_t)row * 2304 + 768 + hh * 64 + c8);
        else
            *(uint4*)(Ks + row * KS_STR + c8) = make_uint4(0, 0, 0, 0);
    }
    for (int idx = t; idx < 64 * 8; idx += 256) {
        int row = idx >> 3, c8 = (idx & 7) * 8;
        int gq = qoff + row; if (gq > NTOK - 1) gq = NTOK - 1;
        *(uint4*)(Qs + row * KS_STR + c8) =
            *(const uint4*)(base + (size_t)gq * 2304 + hh * 64 + c8);
    }
    for (int idx = t; idx < NTOK * 8; idx += 256) {
        int k = idx >> 3, dg = (idx & 7) * 8;
        _Float16 tmp[8];
        *(uint4*)tmp = *(const uint4*)(base + (size_t)k * 2304 + 1536 + hh * 64 + dg);
        #pragma unroll
        for (int j = 0; j < 8; j++) Vt[(dg + j) * AT_STR + k] = tmp[j];
    }
    for (int idx = t; idx < 64 * 27; idx += 256) {     // zero Vt cols 197..223
        int d = idx / 27, k = NTOK + idx % 27;
        Vt[d * AT_STR + k] = (_Float16)0.f;
    }
    __syncthreads();

    // ---- S = Q K^T : wave handles 16 q rows x 13 k-tiles ----
    int wq0 = w * 16;
    f32x4 sacc[13];
    #pragma unroll
    for (int tt = 0; tt < 13; tt++) sacc[tt] = (f32x4){0.f, 0.f, 0.f, 0.f};

    __builtin_amdgcn_s_setprio(1);
    #pragma unroll
    for (int s = 0; s < 2; s++) {
        s8v af = *(const s8v*)(Qs + (wq0 + rl) * KS_STR + s * 32 + 8 * g);
        #pragma unroll
        for (int tt = 0; tt < 13; tt++) {
            s8v bf = *(const s8v*)(Ks + (tt * 16 + rl) * KS_STR + s * 32 + 8 * g);
            sacc[tt] = MfmaF16Call<mfma16_v>::run(af, bf, sacc[tt]);
        }
    }
    __builtin_amdgcn_s_setprio(0);
    __syncthreads();   // all waves done reading Qs/Ks before P overwrites

    // ---- softmax (lane holds col=rl+16*tt for row g*4+r) ----
    _Float16* Pw = Pl + wq0 * AT_STR;
    #pragma unroll
    for (int r = 0; r < 4; r++) {
        float vv[13];
        float mx = -3.0e38f;
        #pragma unroll
        for (int tt = 0; tt < 13; tt++) {
            float v = sacc[tt][r] * 0.125f;
            vv[tt] = v;
            if (rl + 16 * tt < NTOK) mx = fmaxf(mx, v);
        }
        mx = fmaxf(mx, __shfl_xor(mx, 1));
        mx = fmaxf(mx, __shfl_xor(mx, 2));
        mx = fmaxf(mx, __shfl_xor(mx, 4));
        mx = fmaxf(mx, __shfl_xor(mx, 8));
        float pv[13];
        float sum = 0.f;
        #pragma unroll
        for (int tt = 0; tt < 13; tt++) {
            float p = (rl + 16 * tt < NTOK) ? __expf(vv[tt] - mx) : 0.f;
            pv[tt] = p; sum += p;
        }
        sum += __shfl_xor(sum, 1);
        sum += __shfl_xor(sum, 2);
        sum += __shfl_xor(sum, 4);
        sum += __shfl_xor(sum, 8);
        float rinv = 1.0f / sum;
        int prow = g * 4 + r;
        #pragma unroll
        for (int tt = 0; tt < 13; tt++)
            Pw[prow * AT_STR + rl + 16 * tt] = (_Float16)(pv[tt] * rinv);
    }
    for (int idx = lane; idx < 16 * 16; idx += 64) {   // zero P cols 208..223
        int rr = idx >> 4, cc = 208 + (idx & 15);
        Pw[rr * AT_STR + cc] = (_Float16)0.f;
    }
    // no barrier: each wave reads only its own Pw region + stable Vt

    // ---- O = P V : 4 n-tiles, 7 k-steps ----
    f32x4 oacc[4];
    #pragma unroll
    for (int j = 0; j < 4; j++) oacc[j] = (f32x4){0.f, 0.f, 0.f, 0.f};

    __builtin_amdgcn_s_setprio(1);
    for (int s = 0; s < 7; s++) {
        s8v pf = *(const s8v*)(Pw + rl * AT_STR + s * 32 + 8 * g);
        s8v vf[4];
        #pragma unroll
        for (int j = 0; j < 4; j++)
            vf[j] = *(const s8v*)(Vt + (j * 16 + rl) * AT_STR + s * 32 + 8 * g);
        #pragma unroll
        for (int j = 0; j < 4; j++)
            oacc[j] = MfmaF16Call<mfma16_v>::run(pf, vf[j], oacc[j]);
    }
    __builtin_amdgcn_s_setprio(0);

    #pragma unroll
    for (int j = 0; j < 4; j++) {
        #pragma unroll
        for (int r = 0; r < 4; r++) {
            int qidx = qoff + wq0 + g * 4 + r;
            if (qidx < NTOK) {
                int d = j * 16 + rl;
                O[((size_t)n * NTOK + qidx) * DMODEL + hh * 64 + d] =
                    __float2bfloat16(oacc[j][r]);
            }
        }
    }
}

// ---------------- weight convert + transpose (fp32 [K][N] -> bf16 [N][K]) ----
// 32K x 128N tile: 512B coalesced fp32 reads/row, conflict-free LDS, 32B writes.
__device__ inline void transpose_tile_wide(const float* __restrict__ src,
                                           __hip_bfloat16* __restrict__ dst,
                                           int K, int N, int b)
{
    __shared__ float tl[32][129];
    int ntn = N >> 7;
    int n0 = (b % ntn) * 128, k0 = (b / ntn) * 32;
    int t = threadIdx.x;
    #pragma unroll
    for (int i = 0; i < 16; i++) {
        int idx = i * 256 + t;
        int kk = idx >> 7, nn = idx & 127;
        tl[kk][nn] = src[(size_t)(k0 + kk) * N + n0 + nn];
    }
    __syncthreads();
    int n = t >> 1, kc = (t & 1) * 16;
    __hip_bfloat16 v[16];
    #pragma unroll
    for (int j = 0; j < 16; j++) v[j] = __float2bfloat16(tl[kc + j][n]);
    *(uint4*)(dst + (size_t)(n0 + n) * K + k0 + kc)     = *(uint4*)&v[0];
    *(uint4*)(dst + (size_t)(n0 + n) * K + k0 + kc + 8) = *(uint4*)&v[8];
}

// one dispatch: all 12 layers (qkv|proj|fc1|fc2) + patch_w
// per-layer tiles: qkv 432, proj 144, fc1 576, fc2 576 = 1728; patch 144
__global__ __launch_bounds__(256) void convT_all(
    const float* __restrict__ qkv_w, const float* __restrict__ proj_w,
    const float* __restrict__ fc1_w, const float* __restrict__ fc2_w,
    const float* __restrict__ patch_w,
    __hip_bfloat16* __restrict__ wbuf, __hip_bfloat16* __restrict__ patchT)
{
    int b = blockIdx.x;
    if (b < 20736) {
        int layer = b / 1728, rem = b % 1728;
        __hip_bfloat16* wl = wbuf + (size_t)layer * 7077888;
        const float* src; __hip_bfloat16* dst; int K, N, tb;
        if (rem < 432)       { tb = rem;        src = qkv_w  + (size_t)layer * 768 * 2304; dst = wl;           K = 768;  N = 2304; }
        else if (rem < 576)  { tb = rem - 432;  src = proj_w + (size_t)layer * 768 * 768;  dst = wl + 1769472; K = 768;  N = 768;  }
        else if (rem < 1152) { tb = rem - 576;  src = fc1_w  + (size_t)layer * 768 * 3072; dst = wl + 2359296; K = 768;  N = 3072; }
        else                 { tb = rem - 1152; src = fc2_w  + (size_t)layer * 3072 * 768; dst = wl + 4718592; K = 3072; N = 768;  }
        transpose_tile_wide(src, dst, K, N, tb);
    } else {
        transpose_tile_wide(patch_w, patchT, 768, 768, b - 20736);
    }
}

// ---------------- patch extraction (fp32 img -> bf16 patch matrix) ----------------
__global__ __launch_bounds__(256) void patch_extract_kernel(
    const float* __restrict__ img, __hip_bfloat16* __restrict__ Pm)
{
    size_t e = (size_t)blockIdx.x * 256 + threadIdx.x;
    if (e >= (size_t)NPATCH * DMODEL) return;
    int cidx = (int)(e % DMODEL);
    int r    = (int)(e / DMODEL);
    int n  = r / 196, s = r % 196;
    int hi = s / HF, wi = s % HF;
    int c  = cidx >> 8, py = (cidx >> 4) & 15, px = cidx & 15;
    Pm[e] = __float2bfloat16(
        img[(((size_t)n * 3 + c) * 224 + hi * 16 + py) * 224 + wi * 16 + px]);
}

// ---------------- 4x4 inverse (adjugate) ----------------
__device__ void invert4(const float m[16], float out[16]) {
    float inv[16];
    inv[0] = m[5]*m[10]*m[15] - m[5]*m[11]*m[14] - m[9]*m[6]*m[15] + m[9]*m[7]*m[14] + m[13]*m[6]*m[11] - m[13]*m[7]*m[10];
    inv[4] = -m[4]*m[10]*m[15] + m[4]*m[11]*m[14] + m[8]*m[6]*m[15] - m[8]*m[7]*m[14] - m[12]*m[6]*m[11] + m[12]*m[7]*m[10];
    inv[8] = m[4]*m[9]*m[15] - m[4]*m[11]*m[13] - m[8]*m[5]*m[15] + m[8]*m[7]*m[13] + m[12]*m[5]*m[11] - m[12]*m[7]*m[9];
    inv[12] = -m[4]*m[9]*m[14] + m[4]*m[10]*m[13] + m[8]*m[5]*m[14] - m[8]*m[6]*m[13] - m[12]*m[5]*m[10] + m[12]*m[6]*m[9];
    inv[1] = -m[1]*m[10]*m[15] + m[1]*m[11]*m[14] + m[9]*m[2]*m[15] - m[9]*m[3]*m[14] - m[13]*m[2]*m[11] + m[13]*m[3]*m[10];
    inv[5] = m[0]*m[10]*m[15] - m[0]*m[11]*m[14] - m[8]*m[2]*m[15] + m[8]*m[3]*m[14] + m[12]*m[2]*m[11] - m[12]*m[3]*m[10];
    inv[9] = -m[0]*m[9]*m[15] + m[0]*m[11]*m[13] + m[8]*m[1]*m[15] - m[8]*m[3]*m[13] - m[12]*m[1]*m[11] + m[12]*m[3]*m[9];
    inv[13] = m[0]*m[9]*m[14] - m[0]*m[10]*m[13] - m[8]*m[1]*m[14] + m[8]*m[2]*m[13] + m[12]*m[1]*m[10] - m[12]*m[2]*m[9];
    inv[2] = m[1]*m[6]*m[15] - m[1]*m[7]*m[14] - m[5]*m[2]*m[15] + m[5]*m[3]*m[14] + m[13]*m[2]*m[7] - m[13]*m[3]*m[6];
    inv[6] = -m[0]*m[6]*m[15] + m[0]*m[7]*m[14] + m[4]*m[2]*m[15] - m[4]*m[3]*m[14] - m[12]*m[2]*m[7] + m[12]*m[3]*m[6];
    inv[10] = m[0]*m[5]*m[15] - m[0]*m[7]*m[13] - m[4]*m[1]*m[15] + m[4]*m[3]*m[13] + m[12]*m[1]*m[7] - m[12]*m[3]*m[5];
    inv[14] = -m[0]*m[5]*m[14] + m[0]*m[6]*m[13] + m[4]*m[1]*m[14] - m[4]*m[2]*m[13] - m[12]*m[1]*m[6] + m[12]*m[2]*m[5];
    inv[3] = -m[1]*m[6]*m[11] + m[1]*m[7]*m[10] + m[5]*m[2]*m[11] - m[5]*m[3]*m[10] - m[9]*m[2]*m[7] + m[9]*m[3]*m[6];
    inv[7] = m[0]*m[6]*m[11] - m[0]*m[7]*m[10] - m[4]*m[2]*m[11] + m[4]*m[3]*m[10] + m[8]*m[2]*m[7] - m[8]*m[3]*m[6];
    inv[11] = -m[0]*m[5]*m[11] + m[0]*m[7]*m[9] + m[4]*m[1]*m[11] - m[4]*m[3]*m[9] - m[8]*m[1]*m[7] + m[8]*m[3]*m[5];
    inv[15] = m[0]*m[5]*m[10] - m[0]*m[6]*m[9] - m[4]*m[1]*m[10] + m[4]*m[2]*m[9] + m[8]*m[1]*m[6] - m[8]*m[2]*m[5];
    float det = m[0]*inv[0] + m[1]*inv[4] + m[2]*inv[8] + m[3]*inv[12];
    det = 1.0f / det;
    for (int i = 0; i < 16; i++) out[i] = inv[i] * det;
}

// ---------------- BEV index / validity ----------------
__global__ __launch_bounds__(256) void bev_index_kernel(
    const float* __restrict__ depths, const float* __restrict__ poses,
    const float* __restrict__ intr, int* __restrict__ idxbuf)
{
    int bv = blockIdx.x;          // 0..7
    int b  = bv / 4;
    __shared__ float c2w[16];
    if (threadIdx.x == 0) {
        float w2c[16];
        const float* Pm = poses + bv * 16;
        const int perm[4] = {1, 0, 2, 3};
        for (int i = 0; i < 4; i++)
            for (int j = 0; j < 4; j++)
                w2c[i * 4 + j] = Pm[perm[i] * 4 + j];
        invert4(w2c, c2w);
    }
    __syncthreads();
    int t = threadIdx.x;
    if (t >= 196) return;
    int hh = t / HF, ww = t % HF;
    const float* dp = depths + (size_t)bv * 224 * 224;
    int r0 = hh * 16 + 7, c0 = ww * 16 + 7;
    float d = 0.25f * (dp[r0 * 224 + c0] + dp[r0 * 224 + c0 + 1] +
                       dp[(r0 + 1) * 224 + c0] + dp[(r0 + 1) * 224 + c0 + 1]);
    d *= 65.535f;
    bool mask = (d > 0.0f) && (d < 5.0f);
    float fx = intr[bv * 9 + 0], fy = intr[bv * 9 + 4];
    float cx = intr[bv * 9 + 2], cy = intr[bv * 9 + 5];
    float u = (float)ww, v = (float)hh;
    float Xc = -((u - cx) * d / (fx + 1e-8f));
    float Yc = (v - cy) * d / (fy + 1e-8f);
    float Xw = c2w[0] * Xc + c2w[1] * Yc + c2w[2] * d + c2w[3];
    float Yw = c2w[4] * Xc + c2w[5] * Yc + c2w[6] * d + c2w[7];
    float px = Xw * 1.4f + 7.0f;
    float py = -(Yw * 1.4f) + 7.0f;
    int pxi = (int)rintf(px);
    int pyi = (int)rintf(py);
    bool inb = (pxi >= 0) && (pxi < HF) && (pyi >= 0) && (pyi < HF);
    idxbuf[bv * 196 + t] = (mask && inb) ? (b * 196 + pyi * HF + pxi) : -1;
}

// ---------------- scatter (segment sum / count / max) ----------------
__global__ __launch_bounds__(256) void splat_kernel(
    const float* __restrict__ src, const int* __restrict__ idxbuf,
    float* __restrict__ ssum, float* __restrict__ smax, float* __restrict__ cnt)
{
    int r = blockIdx.x;              // 0..1567
    int idx = idxbuf[r];
    if (idx < 0) return;
    int bv = r / 196, s = r % 196;
    const float* row = src + ((size_t)bv * NTOK + 1 + s) * DMODEL;
    int t = threadIdx.x;
    for (int d = t; d < DMODEL; d += 256) {
        float v = row[d];
        atomicAdd(&ssum[(size_t)idx * DMODEL + d], v);
        atomicMax((int*)(smax + (size_t)idx * DMODEL + d), __float_as_int(v));
    }
    if (t == 0) atomicAdd(&cnt[idx], 1.0f);
}

// ---------------- bev combine + 1x1 conv ----------------
__global__ __launch_bounds__(256) void bev_conv_kernel(
    const float* __restrict__ ssum, const float* __restrict__ smax,
    const float* __restrict__ cnt, const float* __restrict__ convw,
    const float* __restrict__ convb, float* __restrict__ out)
{
    int cell = blockIdx.x;           // 0..391
    __shared__ float bev[DMODEL];
    int t = threadIdx.x;
    float c = cnt[cell];
    for (int d = t; d < DMODEL; d += 256)
        bev[d] = 0.5f * (ssum[(size_t)cell * DMODEL + d] / (c + 1e-8f) +
                         smax[(size_t)cell * DMODEL + d]);
    __syncthreads();
    float acc = convb[t];
    const float4* wr = (const float4*)(convw + (size_t)t * DMODEL);
    #pragma unroll 4
    for (int dc = 0; dc < DMODEL / 4; dc++) {
        float4 w4 = wr[dc];
        acc += bev[dc * 4 + 0] * w4.x + bev[dc * 4 + 1] * w4.y +
               bev[dc * 4 + 2] * w4.z + bev[dc * 4 + 3] * w4.w;
    }
    int b = cell / 196, s = cell % 196;
    out[((size_t)b * FD + t) * 196 + s] = acc;
}

// ---------------- host launcher ----------------
extern "C" void kernel_launch(void* const* d_in, const int* in_sizes, int n_in,
                              void* d_out, int out_size, void* d_ws, size_t ws_size,
                              hipStream_t stream) {
    const float* imgs    = (const float*)d_in[0];
    const float* depths  = (const float*)d_in[1];
    const float* poses   = (const float*)d_in[2];
    const float* intr    = (const float*)d_in[3];
    const float* patch_w = (const float*)d_in[5];
    const float* patch_b = (const float*)d_in[6];
    const float* cls_tok = (const float*)d_in[7];
    const float* pos_emb = (const float*)d_in[8];
    const float* ln1_g   = (const float*)d_in[9];
    const float* ln1_b   = (const float*)d_in[10];
    const float* qkv_w   = (const float*)d_in[11];
    const float* qkv_b   = (const float*)d_in[12];
    const float* proj_w  = (const float*)d_in[13];
    const float* proj_b  = (const float*)d_in[14];
    const float* ln2_g   = (const float*)d_in[15];
    const float* ln2_b   = (const float*)d_in[16];
    const float* fc1_w   = (const float*)d_in[17];
    const float* fc1_b   = (const float*)d_in[18];
    const float* fc2_w   = (const float*)d_in[19];
    const float* fc2_b   = (const float*)d_in[20];
    const float* nf_g    = (const float*)d_in[21];
    const float* nf_b    = (const float*)d_in[22];
    const float* conv_w  = (const float*)d_in[23];
    const float* conv_b  = (const float*)d_in[24];
    float* out = (float*)d_out;
    float* ws  = (float*)d_ws;

    // ---- workspace layout (float-slot offsets) ----
    const size_t OFF_TOK  = 0;                    // fp32 [1576][768]
    const size_t OFF_FB   = 1210368;              // fp32 partials [4][1576][768] / patch tmp
    const size_t OFF_PB   = 6051840;              // qkv f16 | mlp bf16 | final-LN fp32
    const size_t OFF_HB   = 8472576;              // bf16 [1576][768]
    const size_t OFF_PT   = 9077760;              // bf16 patchT [768][768]
    const size_t OFF_SSUM = 9372672;
    const size_t OFF_SMAX = 9673728;
    const size_t OFF_CNT  = 9974784;
    const size_t OFF_IDX  = 9975296;
    const size_t OFF_W    = 9977344;              // bf16 12x7077888 (170 MB)

    float* tok  = ws + OFF_TOK;
    float* fbig = ws + OFF_FB;
    float* pbuf = ws + OFF_PB;
    _Float16* qkv_h = (_Float16*)pbuf;
    __hip_bfloat16* hb  = (__hip_bfloat16*)(ws + OFF_HB);
    __hip_bfloat16* pT  = (__hip_bfloat16*)(ws + OFF_PT);
    __hip_bfloat16* wbuf = (__hip_bfloat16*)(ws + OFF_W);
    float* ssum = ws + OFF_SSUM;
    float* smax = ws + OFF_SMAX;
    float* cnt  = ws + OFF_CNT;
    int*   idxb = (int*)(ws + OFF_IDX);

    const int MT = (NROWS + 63) / 64;     // 25
    const int MTP = (NPATCH + 63) / 64;   // 25

    // ---- all weight conversion in one dispatch ----
    convT_all<<<20880, 256, 0, stream>>>(qkv_w, proj_w, fc1_w, fc2_w, patch_w, wbuf, pT);

    // ---- patch embedding + layer-0 LN ----
    patch_extract_kernel<<<(NPATCH * DMODEL) / 256, 256, 0, stream>>>(imgs, hb);
    gemm_t<64, 64><<<dim3(12 * MTP, 1, 1), 256, 0, stream>>>(
        hb, pT, patch_b, nullptr, fbig, NPATCH, 768, 768, 0, 12, nullptr);
    assemble_ln_kernel<<<NROWS, 256, 0, stream>>>(
        fbig, cls_tok, pos_emb, ln1_g, ln1_b, tok, hb);

    // ---- transformer blocks (R8 config + attn setprio + fc2 S=4) ----
    for (int l = 0; l < 12; l++) {
        __hip_bfloat16* wl  = wbuf + (size_t)l * 7077888;
        __hip_bfloat16* wq  = wl;
        __hip_bfloat16* wp  = wl + 1769472;
        __hip_bfloat16* wf1 = wl + 2359296;
        __hip_bfloat16* wf2 = wl + 4718592;

        gemm_t<64, 128><<<dim3(18 * MT, 1, 1), 256, 0, stream>>>(
            hb, wq, qkv_b + (size_t)l * 2304, nullptr, qkv_h, NROWS, 2304, 768,
            4 /*f16*/, 18, nullptr);
        fused_attn_kernel<<<dim3(NIMG * NHEADS, 4), 256, 0, stream>>>(qkv_h, hb);
        gemm_t<64, 64><<<dim3(12 * MT, 1, 2), 256, 0, stream>>>(
            hb, wp, nullptr, nullptr, nullptr, NROWS, 768, 768,
            8 /*partial*/, 12, fbig);
        redln_kernel<2, 0><<<NROWS, 256, 0, stream>>>(
            fbig, proj_b + (size_t)l * DMODEL, tok,
            ln2_g + l * DMODEL, ln2_b + l * DMODEL, hb, nullptr);
        gemm_t<64, 128><<<dim3(24 * MT, 1, 1), 256, 0, stream>>>(
            hb, wf1, fc1_b + (size_t)l * MLPD, nullptr, pbuf, NROWS, 3072, 768,
            3 /*gelu|bf16*/, 24, nullptr);
        gemm_t<64, 64><<<dim3(12 * MT, 1, 4), 256, 0, stream>>>(
            (__hip_bfloat16*)pbuf, wf2, nullptr, nullptr, nullptr, NROWS, 768, 3072,
            8 /*partial*/, 12, fbig);
        if (l < 11) {
            redln_kernel<4, 0><<<NROWS, 256, 0, stream>>>(
                fbig, fc2_b + (size_t)l * DMODEL, tok,
                ln1_g + (l + 1) * DMODEL, ln1_b + (l + 1) * DMODEL, hb, nullptr);
        } else {
            redln_kernel<4, 1><<<NROWS, 256, 0, stream>>>(
                fbig, fc2_b + (size_t)l * DMODEL, tok,
                nf_g, nf_b, nullptr, pbuf);
        }
    }

    // ---- BEV splat ----
    bev_index_kernel<<<NIMG, 256, 0, stream>>>(depths, poses, intr, idxb);
    hipMemsetAsync(ssum, 0, (2 * (size_t)NCELL * DMODEL + 512) * sizeof(float), stream);
    splat_kernel<<<NPATCH, 256, 0, stream>>>(pbuf, idxb, ssum, smax, cnt);

    // ---- bev combine + conv ----
    bev_conv_kernel<<<NCELL, 256, 0, stream>>>(ssum, smax, cnt, conv_w, conv_b, out);
}